// Round 4
// baseline (14322.823 us; speedup 1.0000x reference)
//
#include <hip/hip_runtime.h>

#define SEQ 999
#define HID 256
#define DTC 0.01f
#define CREG 104          // h2-cols in VGPRs per row (2 rows/thread)
#define CLDSU2 12         // 8-byte LDS words per row (24 h2-cols)
#define NXW 125           // xw chunk blocks (8 timesteps each)
#define NW1 128           // W1 blocks (2 rows each)
#define SY_C0 0
#define SY_C1 1
#define SY_CW1 2
#define SY_FLG 4          // flags[0..124]

typedef _Float16 h2 __attribute__((ext_vector_type(2)));
typedef unsigned long long u64;

__device__ __forceinline__ h2 u2h(unsigned u){ return __builtin_bit_cast(h2, u); }
__device__ __forceinline__ unsigned h2u(h2 v){ return __builtin_bit_cast(unsigned, v); }

// v_dot2_f32_f16: src0 = h pair (SGPR), src1 = weight (VGPR, tied so it stays resident), src2/dst = acc.
#define DOT(ACC, HS, WV) asm("v_dot2_f32_f16 %0, %2, %1, %0" : "+v"(ACC), "+v"(WV) : "s"(HS))
#define DOTL(ACC, HS, WU) asm("v_dot2_f32_f16 %0, %1, %2, %0" : "+v"(ACC) : "s"(HS), "v"(WU))

__device__ __forceinline__ unsigned sel4(uint4 v, int k){
  return k==0 ? v.x : k==1 ? v.y : k==2 ? v.z : v.w;   // k compile-time post-unroll
}

__device__ __forceinline__ float softplusf(float x){
  return fmaxf(x, 0.f) + log1pf(__expf(-fabsf(x)));
}
__device__ __forceinline__ float sigmoidf(float x){
  return 1.f/(1.f + __expf(-x));
}
__device__ __forceinline__ float tanh_fast(float x){
  float e = __expf(-2.f*x);
  return (1.f - e)/(1.f + e);
}

__device__ __forceinline__ void waitge(unsigned* p, unsigned v){
  while (__hip_atomic_load(p, __ATOMIC_ACQUIRE, __HIP_MEMORY_SCOPE_AGENT) < v)
    __builtin_amdgcn_s_sleep(8);
}

// Load 2 weight rows: cols 0..103 -> VGPR arrays, cols 104..127 -> LDS (self-owned slots).
#define LOADW(WR, R0, R1, WVA, WVB, WL, TID) do{                                   \
  const uint4* _s0=(const uint4*)((WR)+(size_t)(R0)*128);                          \
  const uint4* _s1=(const uint4*)((WR)+(size_t)(R1)*128);                          \
  _Pragma("unroll")                                                                \
  for(int q=0;q<26;++q){ uint4 v0=_s0[q], v1=_s1[q];                               \
    WVA[4*q]=v0.x; WVA[4*q+1]=v0.y; WVA[4*q+2]=v0.z; WVA[4*q+3]=v0.w;              \
    WVB[4*q]=v1.x; WVB[4*q+1]=v1.y; WVB[4*q+2]=v1.z; WVB[4*q+3]=v1.w; }            \
  _Pragma("unroll")                                                                \
  for(int qq=0;qq<6;++qq){ uint4 v0=_s0[26+qq], v1=_s1[26+qq];                     \
    WL[0][2*qq][TID]=((u64)v0.y<<32)|v0.x; WL[0][2*qq+1][TID]=((u64)v0.w<<32)|v0.z;\
    WL[1][2*qq][TID]=((u64)v1.y<<32)|v1.x; WL[1][2*qq+1][TID]=((u64)v1.w<<32)|v1.z;}\
}while(0)

// Dual-row 256-wide dot: h2[j] = lane j>>2, comp j&3 of HV; readlane -> SGPR -> dot2.
#define DOT2ROWS(HV, WVA, WVB, A0, A1, WL, TID) do{                                \
  float _b0=0.f,_b1=0.f;                                                           \
  _Pragma("unroll")                                                                \
  for (int j=0;j<CREG;++j){                                                        \
    unsigned hh=(unsigned)__builtin_amdgcn_readlane((int)sel4(HV,j&3),j>>2);       \
    if(j&1){ DOT(_b0,hh,WVA[j]); DOT(_b1,hh,WVB[j]); }                             \
    else   { DOT(A0,hh,WVA[j]);  DOT(A1,hh,WVB[j]); }                              \
  }                                                                                \
  _Pragma("unroll")                                                                \
  for (int q=0;q<CLDSU2;++q){                                                      \
    const int _ja=CREG+2*q, _jb=_ja+1;                                             \
    unsigned ha=(unsigned)__builtin_amdgcn_readlane((int)sel4(HV,_ja&3),_ja>>2);   \
    unsigned hb=(unsigned)__builtin_amdgcn_readlane((int)sel4(HV,_jb&3),_jb>>2);   \
    u64 _u0=*(volatile u64*)&WL[0][q][TID];                                        \
    u64 _u1=*(volatile u64*)&WL[1][q][TID];                                        \
    DOTL(A0,ha,(unsigned)_u0); DOTL(_b0,hb,(unsigned)(_u0>>32));                   \
    DOTL(A1,ha,(unsigned)_u1); DOTL(_b1,hb,(unsigned)(_u1>>32));                   \
  }                                                                                \
  A0 += _b0; A1 += _b1;                                                            \
}while(0)

// ---- init: zero the sync area (flags/counters) every call -> determinism ----
__global__ void k_init(unsigned* sync){
  sync[threadIdx.x] = 0u;
}

// ---- weight conversion: whh0/wih1/whh1 -> ROW-MAJOR f16 pairs; bias sums ----
__global__ void k_convert(const float* __restrict__ whh0, const float* __restrict__ wih1,
                          const float* __restrict__ whh1,
                          const float* __restrict__ bih0, const float* __restrict__ bhh0,
                          const float* __restrict__ bih1, const float* __restrict__ bhh1,
                          h2* __restrict__ whh0R, h2* __restrict__ wih1R, h2* __restrict__ whh1R,
                          float* __restrict__ bs0, float* __restrict__ bs1){
  int o = blockIdx.x*256 + threadIdx.x;
  if (o < 131072){
    int r = o >> 7, c2 = o & 127;
    const float* s = whh0 + r*256 + 2*c2;
    whh0R[o] = h2{(_Float16)s[0], (_Float16)s[1]};
  } else if (o < 262144){
    int oo = o - 131072; int r = oo >> 7, c2 = oo & 127;
    const float* s = wih1 + r*256 + 2*c2;
    wih1R[oo] = h2{(_Float16)s[0], (_Float16)s[1]};
  } else if (o < 393216){
    int oo = o - 262144; int r = oo >> 7, c2 = oo & 127;
    const float* s = whh1 + r*256 + 2*c2;
    whh1R[oo] = h2{(_Float16)s[0], (_Float16)s[1]};
  } else if (o < 394240){
    int r = o - 393216; bs0[r] = bih0[r] + bhh0[r];
  } else if (o < 395264){
    int r = o - 394240; bs1[r] = bih1[r] + bhh1[r];
  }
}

// ================= fused pipeline kernel: 256 blocks = 256 CUs =================
// role 0: LSTM layer0 | 1..125: xw1 chunks | 126: LSTM layer1 | 127..254: W1 | 255: head

template<int MODE>
__device__ __forceinline__ void do_layer(
    const h2* wR, const float* wih0, const float* bs, const float* X,
    const float* xw1, _Float16* h0h, float* h1f, unsigned* sync,
    u64 (*wlds)[CLDSU2][512], _Float16* hbuf, float (*exch)[256], float* xlds)
{
  const int tid = threadIdx.x;
  const int r0 = tid, r1 = tid + 512;
  unsigned wva[CREG], wvb[CREG];
  LOADW(wR, r0, r1, wva, wvb, wlds, tid);

  float bsA=0.f, wxa0=0.f, wxa1=0.f, bsB=0.f, wxb0=0.f, wxb1=0.f;
  float nx0=0.f, nx1=0.f;
  int acq = 0;
  if (MODE == 0){
    bsA = bs[r0]; bsB = bs[r1];
    wxa0 = wih0[2*r0]; wxa1 = wih0[2*r0+1];
    wxb0 = wih0[2*r1]; wxb1 = wih0[2*r1+1];
    for (int i=tid; i<2*SEQ; i+=512) xlds[i] = X[i];
  } else {
    while (acq < 2){ waitge(&sync[SY_FLG+acq], 1u); ++acq; }   // chunks 0,1 ready
    nx0 = xw1[r0]; nx1 = xw1[r1];
  }
  if (tid < 256) hbuf[tid] = (_Float16)0.f;
  float c = 0.f;
  __syncthreads();

  uint4 hv = {0u,0u,0u,0u};
#pragma unroll 1
  for (int t=0; t<SEQ; ++t){
    float a0, a1;
    if (MODE == 0){
      float2 xv = *(const float2*)&xlds[2*t];
      a0 = fmaf(wxa1, xv.y, fmaf(wxa0, xv.x, bsA));
      a1 = fmaf(wxb1, xv.y, fmaf(wxb0, xv.x, bsB));
    } else {
      if ((t & 7) == 0 && t){                       // stay one chunk ahead
        int k = t >> 3;
        int last = (k+1 < NXW) ? k+1 : NXW-1;
        while (acq <= last){ waitge(&sync[SY_FLG+acq], 1u); ++acq; }
      }
      a0 = nx0; a1 = nx1;
      if (t+1 < SEQ){ nx0 = xw1[(size_t)(t+1)*1024 + r0]; nx1 = xw1[(size_t)(t+1)*1024 + r1]; }
    }
    DOT2ROWS(hv, wva, wvb, a0, a1, wlds, tid);

    // rows: r0 in [0,512) = i|f ; r1 in [512,1024) = g|o
    float f_=0.f, o_=0.f;
    if (tid < 256){
      exch[0][tid] = sigmoidf(a0);    // i_k
      exch[1][tid] = tanh_fast(a1);   // g_k
    } else {
      f_ = sigmoidf(a0);              // f_k
      o_ = sigmoidf(a1);              // o_k
    }
    __syncthreads();
    if (tid >= 256){
      const int k2 = tid - 256;
      c = fmaf(f_, c, exch[0][k2]*exch[1][k2]);
      float h = o_ * tanh_fast(c);
      hbuf[k2] = (_Float16)h;
      if (MODE == 0) h0h[t*256 + k2] = (_Float16)h;
      else           h1f[t*256 + k2] = h;
    }
    __syncthreads();                   // drains the h stores (vmcnt before barrier)
    hv = *(const uint4*)((const char*)hbuf + (tid&31)*16);
    if (((t & 7) == 7 || t == SEQ-1) && tid == 0){
      __hip_atomic_store(MODE==0 ? &sync[SY_C0] : &sync[SY_C1], (unsigned)(t+1),
                         __ATOMIC_RELEASE, __HIP_MEMORY_SCOPE_AGENT);
    }
  }
}

__device__ __forceinline__ void do_xw(
    int b, const h2* wR, const float* bs1, const _Float16* h0h, float* xw1,
    unsigned* sync, u64 (*wlds)[CLDSU2][512])
{
  const int tid = threadIdx.x;
  const int r0 = tid, r1 = tid + 512;
  unsigned wva[CREG], wvb[CREG];
  LOADW(wR, r0, r1, wva, wvb, wlds, tid);
  const float bsA = bs1[r0], bsB = bs1[r1];

  const int t0 = 8*b;
  const int tend = (t0+8 < SEQ) ? t0+8 : SEQ;
  waitge(&sync[SY_C0], (unsigned)tend);
#pragma unroll 1
  for (int t=t0; t<tend; ++t){
    uint4 hv = *(const uint4*)((const char*)h0h + (size_t)t*512 + (tid&31)*16);
    float a0 = bsA, a1 = bsB;
    DOT2ROWS(hv, wva, wvb, a0, a1, wlds, tid);
    xw1[(size_t)t*1024 + r0] = a0;
    xw1[(size_t)t*1024 + r1] = a1;
  }
  __syncthreads();                     // all waves' stores drained
  if (tid == 0)
    __hip_atomic_store(&sync[SY_FLG+b], 1u, __ATOMIC_RELEASE, __HIP_MEMORY_SCOPE_AGENT);
}

__device__ __forceinline__ void do_w1(
    int w, const float* W1, const float* b1, const float* h1f, float* z1,
    unsigned* sync, float (*exch)[256])
{
  const int tid = threadIdx.x;
  const int half = tid >> 8, lt = tid & 255;
  const int j = 2*w + half;
  const float* wrow = W1 + (size_t)j * (SEQ*HID);
  float acc = 0.f;
  for (int k=0; k<8; ++k){
    int lo = 128*k, hi = 128*(k+1); if (hi > SEQ) hi = SEQ;
    waitge(&sync[SY_C1], (unsigned)hi);
#pragma unroll 8
    for (int t=lo; t<hi; ++t)
      acc = fmaf(wrow[(size_t)t*256 + lt], h1f[(size_t)t*256 + lt], acc);
  }
  exch[half][lt] = acc; __syncthreads();
  for (int s=128; s>0; s>>=1){
    if (lt < s) exch[half][lt] += exch[half][lt+s];
    __syncthreads();
  }
  if (lt == 0) z1[j] = softplusf(exch[half][0] + b1[j]);
  __syncthreads();
  if (tid == 0)
    __hip_atomic_fetch_add(&sync[SY_CW1], 1u, __ATOMIC_RELEASE, __HIP_MEMORY_SCOPE_AGENT);
}

__device__ __forceinline__ void do_head(
    const float* W2, const float* b2, const float* W3, const float* b3,
    const float* z1, const float* data, float* out, unsigned* sync,
    float (*exch)[256], float* xlds)
{
  const int tid = threadIdx.x;
  waitge(&sync[SY_CW1], (unsigned)NW1);
  float* z1s = &exch[0][0];            // 512 floats span exch[0],exch[1]
  if (tid < 256) z1s[tid] = z1[tid];
  __syncthreads();
  if (tid < 128){
    float acc = b2[tid];
#pragma unroll 8
    for (int k=0;k<256;++k) acc = fmaf(W2[tid*256+k], z1s[k], acc);
    xlds[tid] = softplusf(acc);
  }
  __syncthreads();
  if (tid < 4){
    float a = b3[tid];
#pragma unroll 8
    for (int k=0;k<128;++k) a = fmaf(W3[tid*128+k], xlds[k], a);
    xlds[128+tid] = a;
  }
  __syncthreads();
  if (tid == 0){
    float a = xlds[128], b = xlds[129], cc = xlds[130], d = xlds[131];
    float R = data[0], J = data[1];
#pragma unroll 1
    for (int t=0;t<SEQ;++t){
      float RJ = R*J;
      float Rn = R + DTC*(a*R - b*RJ);
      float Jn = J + DTC*(d*RJ - cc*J);
      out[2*t] = Rn; out[2*t+1] = Jn;
      R = Rn; J = Jn;
    }
  }
}

__global__ __attribute__((amdgpu_flat_work_group_size(512,512), amdgpu_waves_per_eu(2,2)))
void k_fused(const h2* __restrict__ whh0R, const h2* __restrict__ wih1R,
             const h2* __restrict__ whh1R, const float* __restrict__ bs0,
             const float* __restrict__ bs1, const float* __restrict__ Wih0,
             const float* __restrict__ X, _Float16* h0h, float* xw1, float* h1f,
             float* z1, const float* __restrict__ W1, const float* __restrict__ b1,
             const float* __restrict__ W2, const float* __restrict__ b2,
             const float* __restrict__ W3, const float* __restrict__ b3,
             const float* __restrict__ data, float* out, unsigned* sync)
{
  __shared__ u64 wlds[2][CLDSU2][512];          // 96 KB
  __shared__ __align__(16) _Float16 hbuf[256];  // 512 B
  __shared__ __align__(16) float exch[2][256];  // 2 KB
  __shared__ __align__(16) float xlds[2*SEQ];   // 8 KB

  const int role = blockIdx.x;
  if (role == 0)
    do_layer<0>(whh0R, Wih0, bs0, X, nullptr, h0h, nullptr, sync, wlds, hbuf, exch, xlds);
  else if (role <= NXW)
    do_xw(role-1, wih1R, bs1, h0h, xw1, sync, wlds);
  else if (role == NXW+1)
    do_layer<1>(whh1R, nullptr, nullptr, nullptr, xw1, nullptr, h1f, sync, wlds, hbuf, exch, xlds);
  else if (role < NXW+2+NW1)
    do_w1(role-(NXW+2), W1, b1, h1f, z1, sync, exch);
  else
    do_head(W2, b2, W3, b3, z1, data, out, sync, exch, xlds);
}

extern "C" void kernel_launch(void* const* d_in, const int* in_sizes, int n_in,
                              void* d_out, int out_size, void* d_ws, size_t ws_size,
                              hipStream_t stream){
  const float* X    = (const float*)d_in[0];
  const float* data = (const float*)d_in[1];
  const float* Wih0 = (const float*)d_in[2];
  const float* Whh0 = (const float*)d_in[3];
  const float* bih0 = (const float*)d_in[4];
  const float* bhh0 = (const float*)d_in[5];
  const float* Wih1 = (const float*)d_in[6];
  const float* Whh1 = (const float*)d_in[7];
  const float* bih1 = (const float*)d_in[8];
  const float* bhh1 = (const float*)d_in[9];
  const float* W1   = (const float*)d_in[10];
  const float* b1   = (const float*)d_in[11];
  const float* W2   = (const float*)d_in[12];
  const float* b2   = (const float*)d_in[13];
  const float* W3   = (const float*)d_in[14];
  const float* b3   = (const float*)d_in[15];
  float* out = (float*)d_out;

  char* w = (char*)d_ws;
  h2*       whh0R = (h2*)(w + 0);              // 512 KB
  h2*       wih1R = (h2*)(w + 524288);         // 512 KB
  h2*       whh1R = (h2*)(w + 1048576);        // 512 KB
  float*    bs0   = (float*)(w + 1572864);     // 4 KB
  float*    bs1   = (float*)(w + 1576960);     // 4 KB
  _Float16* h0h   = (_Float16*)(w + 1581056);  // 511,488 B
  float*    xw1   = (float*)(w + 2097152);     // 4,091,904 B
  float*    h1f   = (float*)(w + 6189056);     // 1,022,976 B
  float*    z1    = (float*)(w + 7212032);     // 1 KB
  unsigned* sync  = (unsigned*)(w + 7213056);  // 1 KB (c0,c1,cw1,flags[125])

  k_init<<<1, 256, 0, stream>>>(sync);
  k_convert<<<1544, 256, 0, stream>>>(Whh0, Wih1, Whh1, bih0, bhh0, bih1, bhh1,
                                      whh0R, wih1R, whh1R, bs0, bs1);
  k_fused<<<256, 512, 0, stream>>>(whh0R, wih1R, whh1R, bs0, bs1, Wih0, X,
                                   h0h, xw1, h1f, z1, W1, b1, W2, b2, W3, b3,
                                   data, out, sync);
}

// Round 5
// 11861.888 us; speedup vs baseline: 1.2075x; 1.2075x over previous
//
#include <hip/hip_runtime.h>

#define SEQ 999
#define HID 256
#define DTC 0.01f
// Per gate-row (128 h2-cols): 48 in VGPR, 56 in AGPR, 24 in LDS
#define CV 48
#define CA 56
#define CLDSU2 12         // u64 words per row in LDS (24 h2-cols), base col 104

typedef _Float16 h2 __attribute__((ext_vector_type(2)));
typedef unsigned long long u64;

__device__ __forceinline__ h2 u2h(unsigned u){ return __builtin_bit_cast(h2, u); }
__device__ __forceinline__ unsigned h2u(h2 v){ return __builtin_bit_cast(unsigned, v); }

// dot2: h pair from SGPR (src0), weight VGPR (src1), acc tied.
#define DOT(ACC, HS, WV)  asm("v_dot2_f32_f16 %0, %2, %1, %0" : "+v"(ACC), "+v"(WV) : "s"(HS))
#define DOTL(ACC, HS, WU) asm("v_dot2_f32_f16 %0, %1, %2, %0" : "+v"(ACC) : "s"(HS), "v"(WU))
// AGPR-resident weight: explicit read, then dot. "a" = AGPR register class.
#define AGW(AG, V) asm("v_accvgpr_write_b32 %0, %1" : "=a"(AG) : "v"(V))
#define DOTA(ACC, HS, AG) do{ unsigned _tw;                                   \
  asm("v_accvgpr_read_b32 %0, %1" : "=v"(_tw) : "a"(AG));                     \
  asm("v_dot2_f32_f16 %0, %1, %2, %0" : "+v"(ACC) : "s"(HS), "v"(_tw)); }while(0)

__device__ __forceinline__ unsigned sel4(uint4 v, int k){
  return k==0 ? v.x : k==1 ? v.y : k==2 ? v.z : v.w;   // k compile-time post-unroll
}

__device__ __forceinline__ float softplusf(float x){
  return fmaxf(x, 0.f) + log1pf(__expf(-fabsf(x)));
}
__device__ __forceinline__ float sigmoidf(float x){
  return 1.f/(1.f + __expf(-x));
}
__device__ __forceinline__ float tanh_fast(float x){
  float e = __expf(-2.f*x);
  return (1.f - e)/(1.f + e);
}

// Weight conversion.
//  whh0/whh1 -> ROW-MAJOR f16:  wR[r*128 + c2] = (W[r][2c2], W[r][2c2+1])   (k_layer layout)
//  wih1      -> TRANSPOSED f16: wT[c2*1024 + r]                              (k_xw1 layout)
__global__ void k_convert(const float* __restrict__ whh0, const float* __restrict__ wih1,
                          const float* __restrict__ whh1,
                          const float* __restrict__ bih0, const float* __restrict__ bhh0,
                          const float* __restrict__ bih1, const float* __restrict__ bhh1,
                          h2* __restrict__ whh0R, h2* __restrict__ wih1T, h2* __restrict__ whh1R,
                          float* __restrict__ bs0, float* __restrict__ bs1){
  int o = blockIdx.x*256 + threadIdx.x;
  if (o < 131072){
    int r = o >> 7, c2 = o & 127;
    const float* s = whh0 + r*256 + 2*c2;
    whh0R[o] = h2{(_Float16)s[0], (_Float16)s[1]};
  } else if (o < 262144){
    int oo = o - 131072; int r = oo & 1023, c2 = oo >> 10;
    const float* s = wih1 + r*256 + 2*c2;
    wih1T[oo] = h2{(_Float16)s[0], (_Float16)s[1]};
  } else if (o < 393216){
    int oo = o - 262144; int r = oo >> 7, c2 = oo & 127;
    const float* s = whh1 + r*256 + 2*c2;
    whh1R[oo] = h2{(_Float16)s[0], (_Float16)s[1]};
  } else if (o < 394240){
    int r = o - 393216; bs0[r] = bih0[r] + bhh0[r];
  } else if (o < 395264){
    int r = o - 394240; bs1[r] = bih1[r] + bhh1[r];
  }
}

// One workgroup (256 threads, 1 CU, 1 wave/SIMD) = one LSTM layer.
// Thread owns hidden unit tid: gate rows {tid, 256+tid, 512+tid, 768+tid} = {i,f,g,o};
// c,h thread-private; one barrier/step. h distributed via ds_read_b128 gather +
// v_readlane -> SGPR feeding v_dot2_f32_f16.
template<int MODE>  // 0: layer0 (x-projection inline), 1: layer1 (xw precomputed)
__global__ __launch_bounds__(256, 1)
void k_layer(const h2* __restrict__ wR, const float* __restrict__ wih0,
             const float* __restrict__ bs, const float* __restrict__ X,
             const float* __restrict__ xw1, _Float16* __restrict__ hOutHalf,
             float* __restrict__ hOutF32){
  __shared__ u64 wlds[4][CLDSU2][256];                 // 96 KB, 8B lane stride (2-way = free)
  __shared__ __align__(16) _Float16 hbuf[2][256];      // double-buffered h
  __shared__ float xlds[2*SEQ];                        // 8 KB (MODE 0)

  const int tid = threadIdx.x;

  unsigned wv0[CV], wv1[CV], wv2[CV], wv3[CV];         // VGPR weights (cols 0..47)
  unsigned ag0[CA], ag1[CA], ag2[CA], ag3[CA];         // AGPR weights (cols 48..103)

#define LOADROW(R, WV, AG) do{                                                        \
  const uint4* _src = (const uint4*)(wR + (size_t)((R)*256+tid)*128);                 \
  _Pragma("unroll")                                                                   \
  for(int q=0;q<12;++q){ uint4 v=_src[q];                                             \
    WV[4*q]=v.x; WV[4*q+1]=v.y; WV[4*q+2]=v.z; WV[4*q+3]=v.w; }                       \
  _Pragma("unroll")                                                                   \
  for(int q=0;q<14;++q){ uint4 v=_src[12+q];                                          \
    AGW(AG[4*q],v.x); AGW(AG[4*q+1],v.y); AGW(AG[4*q+2],v.z); AGW(AG[4*q+3],v.w); }   \
  _Pragma("unroll")                                                                   \
  for(int q=0;q<6;++q){ uint4 v=_src[26+q];                                           \
    wlds[R][2*q  ][tid]=((u64)v.y<<32)|v.x;                                           \
    wlds[R][2*q+1][tid]=((u64)v.w<<32)|v.z; }                                         \
}while(0)

  LOADROW(0, wv0, ag0);
  LOADROW(1, wv1, ag1);
  LOADROW(2, wv2, ag2);
  LOADROW(3, wv3, ag3);

  float bsr[4], wxa[4], wxb[4], nx[4];
  if (MODE == 0){
#pragma unroll
    for (int r=0;r<4;++r){
      bsr[r] = bs[r*256+tid];
      wxa[r] = wih0[(r*256+tid)*2 + 0];
      wxb[r] = wih0[(r*256+tid)*2 + 1];
    }
    for (int i=tid; i<2*SEQ; i+=256) xlds[i] = X[i];
  } else {
#pragma unroll
    for (int r=0;r<4;++r) nx[r] = xw1[r*256+tid];
  }

  float c = 0.f;
  uint4 hv = {0u,0u,0u,0u};      // h_{-1} = 0
  __syncthreads();

#pragma unroll 1
  for (int t=0; t<SEQ; ++t){
    float a0[4], a1[4];
    if (MODE == 0){
      float2 xv = *(const float2*)&xlds[2*t];
#pragma unroll
      for (int r=0;r<4;++r){
        a0[r] = fmaf(wxb[r], xv.y, fmaf(wxa[r], xv.x, bsr[r]));
        a1[r] = 0.f;
      }
    } else {
#pragma unroll
      for (int r=0;r<4;++r){ a0[r] = nx[r]; a1[r] = 0.f; }
      if (t+1 < SEQ){
#pragma unroll
        for (int r=0;r<4;++r) nx[r] = xw1[(t+1)*1024 + r*256 + tid];
      }
    }

    // ---- cols 0..47: VGPR-resident ----
#pragma unroll
    for (int j=0;j<CV;++j){
      unsigned hh = (unsigned)__builtin_amdgcn_readlane((int)sel4(hv, j&3), j>>2);
      if (j & 1){
        DOT(a1[0], hh, wv0[j]); DOT(a1[1], hh, wv1[j]);
        DOT(a1[2], hh, wv2[j]); DOT(a1[3], hh, wv3[j]);
      } else {
        DOT(a0[0], hh, wv0[j]); DOT(a0[1], hh, wv1[j]);
        DOT(a0[2], hh, wv2[j]); DOT(a0[3], hh, wv3[j]);
      }
    }
    // ---- cols 48..103: AGPR-resident ----
#pragma unroll
    for (int j=CV;j<CV+CA;++j){
      unsigned hh = (unsigned)__builtin_amdgcn_readlane((int)sel4(hv, j&3), j>>2);
      const int k = j - CV;
      if (j & 1){
        DOTA(a1[0], hh, ag0[k]); DOTA(a1[1], hh, ag1[k]);
        DOTA(a1[2], hh, ag2[k]); DOTA(a1[3], hh, ag3[k]);
      } else {
        DOTA(a0[0], hh, ag0[k]); DOTA(a0[1], hh, ag1[k]);
        DOTA(a0[2], hh, ag2[k]); DOTA(a0[3], hh, ag3[k]);
      }
    }
    // ---- cols 104..127: LDS-resident (volatile: stay in-loop) ----
#pragma unroll
    for (int q=0;q<CLDSU2;++q){
      const int ja = CV+CA + 2*q, jb = ja + 1;
      unsigned ha = (unsigned)__builtin_amdgcn_readlane((int)sel4(hv, ja&3), ja>>2);
      unsigned hb = (unsigned)__builtin_amdgcn_readlane((int)sel4(hv, jb&3), jb>>2);
      u64 u0 = *(volatile u64*)&wlds[0][q][tid];
      u64 u1 = *(volatile u64*)&wlds[1][q][tid];
      u64 u2 = *(volatile u64*)&wlds[2][q][tid];
      u64 u3 = *(volatile u64*)&wlds[3][q][tid];
      DOTL(a0[0], ha, (unsigned)u0); DOTL(a1[0], hb, (unsigned)(u0>>32));
      DOTL(a0[1], ha, (unsigned)u1); DOTL(a1[1], hb, (unsigned)(u1>>32));
      DOTL(a0[2], ha, (unsigned)u2); DOTL(a1[2], hb, (unsigned)(u2>>32));
      DOTL(a0[3], ha, (unsigned)u3); DOTL(a1[3], hb, (unsigned)(u3>>32));
    }

    float i_ = sigmoidf(a0[0] + a1[0]);
    float f_ = sigmoidf(a0[1] + a1[1]);
    float g_ = tanh_fast(a0[2] + a1[2]);
    float o_ = sigmoidf(a0[3] + a1[3]);
    c = fmaf(f_, c, i_*g_);
    float h = o_ * tanh_fast(c);

    hbuf[t&1][tid] = (_Float16)h;
    if (MODE == 0) hOutHalf[t*256 + tid] = (_Float16)h;
    else           hOutF32 [t*256 + tid] = h;
    __syncthreads();
    hv = *(const uint4*)((const char*)hbuf[t&1] + (tid&31)*16);   // gather new h
    // next iteration writes hbuf[(t+1)&1] -> no WAR hazard, single barrier suffices
  }
}

// xw1[t][r] = bs1[r] + Wih1[r,:] . h0[t,:]  -- parallel over t
__global__ __launch_bounds__(1024)
void k_xw1(const h2* __restrict__ wih1T, const float* __restrict__ bs1,
           const h2* __restrict__ h0, float* __restrict__ xw1){
  const int tid = threadIdx.x;
#pragma unroll 1
  for (int tt=0; tt<8; ++tt){
    int t = blockIdx.x*8 + tt;
    if (t >= SEQ) return;
    const uint4* hv4 = (const uint4*)(h0 + t*128);
    float acc = bs1[tid];
#pragma unroll
    for (int q=0;q<32;++q){
      uint4 hv = hv4[q];
      acc = __builtin_amdgcn_fdot2(u2h(hv.x), u2h(h2u(wih1T[(4*q+0)*1024 + tid])), acc, false);
      acc = __builtin_amdgcn_fdot2(u2h(hv.y), u2h(h2u(wih1T[(4*q+1)*1024 + tid])), acc, false);
      acc = __builtin_amdgcn_fdot2(u2h(hv.z), u2h(h2u(wih1T[(4*q+2)*1024 + tid])), acc, false);
      acc = __builtin_amdgcn_fdot2(u2h(hv.w), u2h(h2u(wih1T[(4*q+3)*1024 + tid])), acc, false);
    }
    xw1[t*1024 + tid] = acc;
  }
}

// z1[j] = softplus(W1[j,:] . h1_flat + b1[j]); one block per output row, 262 MB streamed once.
__global__ __launch_bounds__(256)
void k_w1(const float* __restrict__ W1, const float* __restrict__ b1,
          const float* __restrict__ h1f, float* __restrict__ z1){
  __shared__ float red[256];
  const int j = blockIdx.x, tid = threadIdx.x;
  const float4* w4 = (const float4*)(W1 + (size_t)j * (SEQ*HID));
  const float4* h4 = (const float4*)h1f;
  float acc = 0.f;
  for (int q = tid; q < (SEQ*HID/4); q += 256){
    float4 w = w4[q], h = h4[q];
    acc = fmaf(w.x, h.x, acc); acc = fmaf(w.y, h.y, acc);
    acc = fmaf(w.z, h.z, acc); acc = fmaf(w.w, h.w, acc);
  }
  red[tid] = acc; __syncthreads();
  for (int s=128; s>0; s>>=1){
    if (tid < s) red[tid] += red[tid+s];
    __syncthreads();
  }
  if (tid == 0) z1[j] = softplusf(red[0] + b1[j]);
}

// MLP tail + 999-step explicit Euler (serial, 1 thread)
__global__ __launch_bounds__(128)
void k_head(const float* __restrict__ W2, const float* __restrict__ b2,
            const float* __restrict__ W3, const float* __restrict__ b3,
            const float* __restrict__ z1, const float* __restrict__ data,
            float* __restrict__ out){
  __shared__ float z1s[256], z2s[128], ab[4];
  const int tid = threadIdx.x;
  z1s[tid] = z1[tid]; z1s[tid+128] = z1[tid+128];
  __syncthreads();
  float acc = b2[tid];
  for (int k=0;k<256;++k) acc = fmaf(W2[tid*256+k], z1s[k], acc);
  z2s[tid] = softplusf(acc);
  __syncthreads();
  if (tid < 4){
    float a = b3[tid];
    for (int k=0;k<128;++k) a = fmaf(W3[tid*128+k], z2s[k], a);
    ab[tid] = a;
  }
  __syncthreads();
  if (tid == 0){
    float a = ab[0], b = ab[1], cc = ab[2], d = ab[3];
    float R = data[0], J = data[1];
#pragma unroll 1
    for (int t=0;t<SEQ;++t){
      float RJ = R*J;
      float Rn = R + DTC*(a*R - b*RJ);
      float Jn = J + DTC*(d*RJ - cc*J);
      out[2*t] = Rn; out[2*t+1] = Jn;
      R = Rn; J = Jn;
    }
  }
}

extern "C" void kernel_launch(void* const* d_in, const int* in_sizes, int n_in,
                              void* d_out, int out_size, void* d_ws, size_t ws_size,
                              hipStream_t stream){
  const float* X    = (const float*)d_in[0];
  const float* data = (const float*)d_in[1];
  const float* Wih0 = (const float*)d_in[2];
  const float* Whh0 = (const float*)d_in[3];
  const float* bih0 = (const float*)d_in[4];
  const float* bhh0 = (const float*)d_in[5];
  const float* Wih1 = (const float*)d_in[6];
  const float* Whh1 = (const float*)d_in[7];
  const float* bih1 = (const float*)d_in[8];
  const float* bhh1 = (const float*)d_in[9];
  const float* W1   = (const float*)d_in[10];
  const float* b1   = (const float*)d_in[11];
  const float* W2   = (const float*)d_in[12];
  const float* b2   = (const float*)d_in[13];
  const float* W3   = (const float*)d_in[14];
  const float* b3   = (const float*)d_in[15];
  float* out = (float*)d_out;

  char* w = (char*)d_ws;
  h2*       whh0R = (h2*)(w + 0);              // 512 KB (row-major f16)
  h2*       wih1T = (h2*)(w + 524288);         // 512 KB (transposed f16)
  h2*       whh1R = (h2*)(w + 1048576);        // 512 KB (row-major f16)
  float*    bs0   = (float*)(w + 1572864);     // 4 KB
  float*    bs1   = (float*)(w + 1576960);     // 4 KB
  _Float16* h0h   = (_Float16*)(w + 1581056);  // 999*256*2 = 511,488 B
  float*    xw1   = (float*)(w + 2097152);     // 999*1024*4 = 4,091,904 B
  float*    h1f   = (float*)(w + 6189056);     // 999*256*4 = 1,022,976 B
  float*    z1    = (float*)(w + 7212032);     // 1 KB   (total ~7.2 MB)

  k_convert<<<1544, 256, 0, stream>>>(Whh0, Wih1, Whh1, bih0, bhh0, bih1, bhh1,
                                      whh0R, wih1T, whh1R, bs0, bs1);
  k_layer<0><<<1, 256, 0, stream>>>(whh0R, Wih0, bs0, X, nullptr, h0h, nullptr);
  k_xw1<<<125, 1024, 0, stream>>>(wih1T, bs1, (const h2*)h0h, xw1);
  k_layer<1><<<1, 256, 0, stream>>>(whh1R, nullptr, bs1, nullptr, xw1, nullptr, h1f);
  k_w1<<<256, 256, 0, stream>>>(W1, b1, h1f, z1);
  k_head<<<1, 128, 0, stream>>>(W2, b2, W3, b3, z1, data, out);
}

// Round 6
// 5904.264 us; speedup vs baseline: 2.4258x; 2.0090x over previous
//
#include <hip/hip_runtime.h>

#define SEQ 999
#define DTC 0.01f
#define NXW 125
#define NW1 64

// sync[] dword indices
#define SY_C0  0     // L0 h progress (every 8 steps)
#define SY_C1  1     // L1 h progress
#define SY_CW1 2     // W1 blocks done
#define SY_GC0 4     // L0 per-gate step counters [4]
#define SY_GC1 8     // L1 per-gate step counters [4]
#define SY_XWF 12    // xw chunk flags [125]

typedef _Float16 h2 __attribute__((ext_vector_type(2)));

__device__ __forceinline__ h2 u2h(unsigned u){ return __builtin_bit_cast(h2,u); }
__device__ __forceinline__ unsigned h2u(h2 v){ return __builtin_bit_cast(unsigned,v); }

// v_dot2_f32_f16: h pair in SGPR (src0), weight tied in VGPR (stays resident), acc tied.
#define DOT(ACC,HS,WV) asm("v_dot2_f32_f16 %0, %2, %1, %0" : "+v"(ACC), "+v"(WV) : "s"(HS))

__device__ __forceinline__ unsigned sel4(uint4 v,int k){
  return k==0?v.x:k==1?v.y:k==2?v.z:v.w;   // k compile-time post-unroll
}

__device__ __forceinline__ float softplusf(float x){
  return fmaxf(x,0.f) + log1pf(__expf(-fabsf(x)));
}
__device__ __forceinline__ float sigmoidf(float x){ return 1.f/(1.f+__expf(-x)); }
__device__ __forceinline__ float tanh_fast(float x){
  float e = __expf(-2.f*x); return (1.f-e)/(1.f+e);
}

__device__ __forceinline__ void waitge8(unsigned* p, unsigned v){
  while (__hip_atomic_load(p,__ATOMIC_ACQUIRE,__HIP_MEMORY_SCOPE_AGENT) < v)
    __builtin_amdgcn_s_sleep(8);
}
__device__ __forceinline__ void waitge1(unsigned* p, unsigned v){
  while (__hip_atomic_load(p,__ATOMIC_ACQUIRE,__HIP_MEMORY_SCOPE_AGENT) < v)
    __builtin_amdgcn_s_sleep(1);
}

// ---- init: zero sync area every call (determinism across graph replays) ----
__global__ void k_init(unsigned* sync){
  if (threadIdx.x < 160) sync[threadIdx.x] = 0u;
}

// ---- weight conversion (same as round 5, proven) ----
__global__ void k_convert(const float* __restrict__ whh0, const float* __restrict__ wih1,
                          const float* __restrict__ whh1,
                          const float* __restrict__ bih0, const float* __restrict__ bhh0,
                          const float* __restrict__ bih1, const float* __restrict__ bhh1,
                          h2* __restrict__ whh0R, h2* __restrict__ wih1T, h2* __restrict__ whh1R,
                          float* __restrict__ bs0, float* __restrict__ bs1){
  int o = blockIdx.x*256 + threadIdx.x;
  if (o < 131072){
    int r = o >> 7, c2 = o & 127;
    const float* s = whh0 + r*256 + 2*c2;
    whh0R[o] = h2{(_Float16)s[0], (_Float16)s[1]};
  } else if (o < 262144){
    int oo = o - 131072; int r = oo & 1023, c2 = oo >> 10;
    const float* s = wih1 + r*256 + 2*c2;
    wih1T[oo] = h2{(_Float16)s[0], (_Float16)s[1]};
  } else if (o < 393216){
    int oo = o - 262144; int r = oo >> 7, c2 = oo & 127;
    const float* s = whh1 + r*256 + 2*c2;
    whh1R[oo] = h2{(_Float16)s[0], (_Float16)s[1]};
  } else if (o < 394240){
    int r = o - 393216; bs0[r] = bih0[r] + bhh0[r];
  } else if (o < 395264){
    int r = o - 394240; bs1[r] = bih1[r] + bhh1[r];
  }
}

// ================= LSTM layer spread over 4 CUs (one gate each) =================
// Block g computes gate-rows [256g, 256g+256). 512 threads: thread = (khalf, unit k).
// Weights for the owned (row, k-half): 64 h2 = 64 VGPRs, register-resident (under the
// 128-VGPR cap). Per step: dots -> LDS k-combine -> publish pre-act (agent atomic) ->
// release own counter / poll 3 peers -> load 3 peer gates -> identical redundant c,h
// update on every CU (bit-identical inputs -> bit-identical h, no h broadcast needed).
template<int MODE>  // 0: layer0 (x-proj inline), 1: layer1 (xw1 from chunk workers)
__device__ void do_layer(int g, const h2* wR, const float* wih0, const float* bs,
                         const float* X, const float* xw1, _Float16* h0h, float* h1f,
                         float* gb, unsigned* gcnt, unsigned* xwflags, unsigned* sync,
                         float* xlds, float* pbuf, _Float16 (*hbuf)[256])
{
  const int tid  = threadIdx.x;
  const int half = tid >> 8;          // k-half (cols 128*half ..)
  const int k    = tid & 255;         // hidden unit within gate
  const int R    = (g<<8) + k;        // global gate row

  unsigned wv[64];                    // 64 h2 weights, register-resident
  {
    const uint4* src = (const uint4*)(wR + (size_t)R*128 + half*64);
#pragma unroll
    for (int q=0;q<16;++q){
      uint4 v = src[q];
      wv[4*q]=v.x; wv[4*q+1]=v.y; wv[4*q+2]=v.z; wv[4*q+3]=v.w;
    }
  }

  float bsv=0.f, wx0=0.f, wx1=0.f;
  if (MODE==0){
    if (half==0){ bsv = bs[R]; wx0 = wih0[2*R]; wx1 = wih0[2*R+1]; }
    for (int i=tid;i<2*SEQ;i+=512) xlds[i] = X[i];
  } else {
    if (tid==0) waitge8(&xwflags[0], 1u);          // chunk 0 (covers t=0 and t=1 prefetch)
  }
  __syncthreads();
  float nx=0.f, nx2=0.f;
  if (MODE==1 && half==0) nx = xw1[R];

  uint4 hv = {0u,0u,0u,0u};           // h_{-1}=0
  float c = 0.f;
  const int lbase = half*16;          // readlane base (wave-uniform)

#pragma unroll 1
  for (int t=0;t<SEQ;++t){
    // issue next-step xw prefetch EARLY so its vmcnt drain lands at B1 (hidden by dots)
    if (MODE==1 && half==0 && t+1<SEQ) nx2 = xw1[(size_t)(t+1)*1024 + R];

    float aA, aB=0.f;
    if (MODE==0){
      float2 xv = *(const float2*)&xlds[2*t];
      aA = (half==0) ? fmaf(wx1, xv.y, fmaf(wx0, xv.x, bsv)) : 0.f;
    } else {
      aA = (half==0) ? nx : 0.f;
    }
#pragma unroll
    for (int jj=0;jj<64;++jj){
      unsigned hh = (unsigned)__builtin_amdgcn_readlane((int)sel4(hv, jj&3), lbase+(jj>>2));
      if (jj&1) DOT(aB, hh, wv[jj]); else DOT(aA, hh, wv[jj]);
    }
    float a = aA + aB;

    if (half==1) pbuf[k] = a;
    __syncthreads();                                   // B1: k-combine ready, prefetch drained
    if (half==0){
      a += pbuf[k];
      __hip_atomic_store(&gb[(t&1)*1024 + (g<<8) + k], a,
                         __ATOMIC_RELAXED, __HIP_MEMORY_SCOPE_AGENT);
    }
    __syncthreads();                                   // B2: all publishes drained (vmcnt)
    if (tid==256)                                      // release (wave 4) never blocked by polls (wave 0)
      __hip_atomic_store(&gcnt[g], (unsigned)(t+1), __ATOMIC_RELEASE, __HIP_MEMORY_SCOPE_AGENT);
    if (tid<4 && tid!=g) waitge1(&gcnt[tid], (unsigned)(t+1));
    if (MODE==1 && tid==4 && t+2<SEQ && ((t+2)&7)==0)  // gate NEXT step's prefetch chunk
      waitge1(&xwflags[(t+2)>>3], 1u);
    __syncthreads();                                   // B3: peers ready
    if (half==0){
      float* gbs = gb + (t&1)*1024;
      float vi = (g==0)? a : __hip_atomic_load(&gbs[      k], __ATOMIC_RELAXED, __HIP_MEMORY_SCOPE_AGENT);
      float vf = (g==1)? a : __hip_atomic_load(&gbs[256 + k], __ATOMIC_RELAXED, __HIP_MEMORY_SCOPE_AGENT);
      float vg = (g==2)? a : __hip_atomic_load(&gbs[512 + k], __ATOMIC_RELAXED, __HIP_MEMORY_SCOPE_AGENT);
      float vo = (g==3)? a : __hip_atomic_load(&gbs[768 + k], __ATOMIC_RELAXED, __HIP_MEMORY_SCOPE_AGENT);
      vi = sigmoidf(vi); vf = sigmoidf(vf); vg = tanh_fast(vg); vo = sigmoidf(vo);
      c = fmaf(vf, c, vi*vg);
      float h = vo * tanh_fast(c);
      hbuf[t&1][k] = (_Float16)h;
      if (g==0){
        if (MODE==0) h0h[t*256+k] = (_Float16)h;
        else         h1f[t*256+k] = h;
      }
      nx = nx2;
    }
    __syncthreads();                                   // B4: hbuf + global h drained
    hv = *(const uint4*)((const char*)hbuf[t&1] + (tid&31)*16);
    if (g==0 && tid==0 && ((t&7)==7 || t==SEQ-1))
      __hip_atomic_store(MODE==0 ? &sync[SY_C0] : &sync[SY_C1], (unsigned)(t+1),
                         __ATOMIC_RELEASE, __HIP_MEMORY_SCOPE_AGENT);
  }
}

// xw chunk worker: xw1[t][r] = bs1[r] + Wih1[r,:]·h0[t,:] for 8 t's (round-1 body, proven)
__device__ void do_xw(int b, const h2* wih1T, const float* bs1, const _Float16* h0h,
                      float* xw1, unsigned* sync, unsigned* xwflags)
{
  const int tid = threadIdx.x;
  const int t0 = b*8;
  const int tend = (t0+8 < SEQ) ? t0+8 : SEQ;
  if (tid==0) waitge8(&sync[SY_C0], (unsigned)tend);
  __syncthreads();
  const float bA = bs1[tid], bB = bs1[tid+512];
#pragma unroll 1
  for (int t=t0;t<tend;++t){
    const uint4* hv4 = (const uint4*)(h0h + (size_t)t*256);
    float a0=bA, a1=bB, b0=0.f, b1=0.f;
#pragma unroll
    for (int q=0;q<32;++q){
      uint4 hv = hv4[q];
      h2 hx=u2h(hv.x), hy=u2h(hv.y), hz=u2h(hv.z), hw=u2h(hv.w);
      a0 = __builtin_amdgcn_fdot2(hx, wih1T[(4*q+0)*1024+tid    ], a0, false);
      b0 = __builtin_amdgcn_fdot2(hy, wih1T[(4*q+1)*1024+tid    ], b0, false);
      a0 = __builtin_amdgcn_fdot2(hz, wih1T[(4*q+2)*1024+tid    ], a0, false);
      b0 = __builtin_amdgcn_fdot2(hw, wih1T[(4*q+3)*1024+tid    ], b0, false);
      a1 = __builtin_amdgcn_fdot2(hx, wih1T[(4*q+0)*1024+tid+512], a1, false);
      b1 = __builtin_amdgcn_fdot2(hy, wih1T[(4*q+1)*1024+tid+512], b1, false);
      a1 = __builtin_amdgcn_fdot2(hz, wih1T[(4*q+2)*1024+tid+512], a1, false);
      b1 = __builtin_amdgcn_fdot2(hw, wih1T[(4*q+3)*1024+tid+512], b1, false);
    }
    xw1[(size_t)t*1024 + tid      ] = a0 + b0;
    xw1[(size_t)t*1024 + tid + 512] = a1 + b1;
  }
  __syncthreads();
  if (tid==0) __hip_atomic_store(&xwflags[b], 1u, __ATOMIC_RELEASE, __HIP_MEMORY_SCOPE_AGENT);
}

// W1 streamer: 4 rows per block, chunk-gated on L1 progress; 262 MB read once.
__device__ void do_w1(int w, const float* W1, const float* b1, const float* h1f,
                      float* z1, unsigned* sync, float* red)
{
  const int tid = threadIdx.x;
#pragma unroll 1
  for (int rr=0;rr<4;++rr){
    const int j = w*4 + rr;
    const float* wrow = W1 + (size_t)j*(SEQ*256);
    float acc = 0.f;
#pragma unroll 1
    for (int kc=0;kc<8;++kc){
      const int lo = kc*128, hi = (kc==7) ? SEQ : lo+128;
      if (tid==0) waitge8(&sync[SY_C1], (unsigned)hi);
      __syncthreads();
      const float4* w4 = (const float4*)(wrow + lo*256);
      const float4* h4 = (const float4*)(h1f + lo*256);
      const int n4 = (hi-lo)*64;
      for (int q=tid; q<n4; q+=512){
        float4 a=w4[q], b=h4[q];
        acc=fmaf(a.x,b.x,acc); acc=fmaf(a.y,b.y,acc);
        acc=fmaf(a.z,b.z,acc); acc=fmaf(a.w,b.w,acc);
      }
      __syncthreads();
    }
    red[tid]=acc; __syncthreads();
    for (int s=256;s>0;s>>=1){ if(tid<s) red[tid]+=red[tid+s]; __syncthreads(); }
    if (tid==0) z1[j] = softplusf(red[0] + b1[j]);
    __syncthreads();
  }
  if (tid==0) __hip_atomic_fetch_add(&sync[SY_CW1], 1u, __ATOMIC_RELEASE, __HIP_MEMORY_SCOPE_AGENT);
}

// MLP tail + Euler
__device__ void do_head(const float* W2, const float* b2, const float* W3, const float* b3,
                        const float* z1, const float* data, float* out,
                        unsigned* sync, float* red)
{
  const int tid = threadIdx.x;
  if (tid==0) waitge8(&sync[SY_CW1], (unsigned)NW1);
  __syncthreads();
  if (tid<256) red[tid] = z1[tid];
  __syncthreads();
  if (tid<128){
    float acc = b2[tid];
#pragma unroll 4
    for (int kk=0;kk<256;++kk) acc = fmaf(W2[tid*256+kk], red[kk], acc);
    red[256+tid] = softplusf(acc);
  }
  __syncthreads();
  if (tid<4){
    float a = b3[tid];
#pragma unroll 4
    for (int kk=0;kk<128;++kk) a = fmaf(W3[tid*128+kk], red[256+kk], a);
    red[384+tid] = a;
  }
  __syncthreads();
  if (tid==0){
    float a=red[384], b=red[385], cc=red[386], d=red[387];
    float R=data[0], J=data[1];
#pragma unroll 1
    for (int t=0;t<SEQ;++t){
      float RJ=R*J;
      float Rn = R + DTC*(a*R - b*RJ);
      float Jn = J + DTC*(d*RJ - cc*J);
      out[2*t]=Rn; out[2*t+1]=Jn;
      R=Rn; J=Jn;
    }
  }
}

// roles: 0-3 L0 gates | 4-7 L1 gates | 8..132 xw chunks | 133..196 W1 | 197 head
__global__ __launch_bounds__(512)
void k_fused(const h2* __restrict__ whh0R, const h2* __restrict__ wih1T,
             const h2* __restrict__ whh1R, const float* __restrict__ bs0,
             const float* __restrict__ bs1, const float* __restrict__ Wih0,
             const float* __restrict__ X, _Float16* h0h, float* xw1, float* h1f,
             float* z1, const float* __restrict__ W1, const float* __restrict__ b1,
             const float* __restrict__ W2, const float* __restrict__ b2,
             const float* __restrict__ W3, const float* __restrict__ b3,
             const float* __restrict__ data, float* out,
             float* gb0, float* gb1, unsigned* sync)
{
  __shared__ char lds_pad[84*1024];               // force 1 block/CU (no role co-tenancy)
  __shared__ float xlds[2*SEQ];
  __shared__ float pbuf[256];
  __shared__ __align__(16) _Float16 hbuf[2][256];
  __shared__ float red[512];
  if (threadIdx.x==0) ((volatile char*)lds_pad)[0] = 0;

  const int role = blockIdx.x;
  if (role < 4)
    do_layer<0>(role, whh0R, Wih0, bs0, X, nullptr, h0h, nullptr,
                gb0, sync+SY_GC0, sync+SY_XWF, sync, xlds, pbuf, hbuf);
  else if (role < 8)
    do_layer<1>(role-4, whh1R, nullptr, nullptr, nullptr, xw1, h0h, h1f,
                gb1, sync+SY_GC1, sync+SY_XWF, sync, xlds, pbuf, hbuf);
  else if (role < 8+NXW)
    do_xw(role-8, wih1T, bs1, h0h, xw1, sync, sync+SY_XWF);
  else if (role < 8+NXW+NW1)
    do_w1(role-(8+NXW), W1, b1, h1f, z1, sync, red);
  else
    do_head(W2, b2, W3, b3, z1, data, out, sync, red);
}

extern "C" void kernel_launch(void* const* d_in, const int* in_sizes, int n_in,
                              void* d_out, int out_size, void* d_ws, size_t ws_size,
                              hipStream_t stream){
  const float* X    = (const float*)d_in[0];
  const float* data = (const float*)d_in[1];
  const float* Wih0 = (const float*)d_in[2];
  const float* Whh0 = (const float*)d_in[3];
  const float* bih0 = (const float*)d_in[4];
  const float* bhh0 = (const float*)d_in[5];
  const float* Wih1 = (const float*)d_in[6];
  const float* Whh1 = (const float*)d_in[7];
  const float* bih1 = (const float*)d_in[8];
  const float* bhh1 = (const float*)d_in[9];
  const float* W1   = (const float*)d_in[10];
  const float* b1   = (const float*)d_in[11];
  const float* W2   = (const float*)d_in[12];
  const float* b2   = (const float*)d_in[13];
  const float* W3   = (const float*)d_in[14];
  const float* b3   = (const float*)d_in[15];
  float* out = (float*)d_out;

  char* w = (char*)d_ws;
  h2*       whh0R = (h2*)(w + 0);              // 512 KB (row-major f16)
  h2*       wih1T = (h2*)(w + 524288);         // 512 KB (transposed f16)
  h2*       whh1R = (h2*)(w + 1048576);        // 512 KB (row-major f16)
  float*    bs0   = (float*)(w + 1572864);     // 4 KB
  float*    bs1   = (float*)(w + 1576960);     // 4 KB
  _Float16* h0h   = (_Float16*)(w + 1581056);  // 511,488 B
  float*    xw1   = (float*)(w + 2097152);     // 4,091,904 B
  float*    h1f   = (float*)(w + 6189056);     // 1,022,976 B
  float*    z1    = (float*)(w + 7212032);     // 1 KB
  float*    gb0   = (float*)(w + 7213056);     // 8 KB  [2][4][256] gate pre-acts L0
  float*    gb1   = (float*)(w + 7221248);     // 8 KB  L1
  unsigned* sync  = (unsigned*)(w + 7229440);  // 640 B counters/flags

  k_init<<<1, 256, 0, stream>>>(sync);
  k_convert<<<1544, 256, 0, stream>>>(Whh0, Wih1, Whh1, bih0, bhh0, bih1, bhh1,
                                      whh0R, wih1T, whh1R, bs0, bs1);
  k_fused<<<8+NXW+NW1+1, 512, 0, stream>>>(whh0R, wih1T, whh1R, bs0, bs1, Wih0, X,
                                           h0h, xw1, h1f, z1, W1, b1, W2, b2, W3, b3,
                                           data, out, gb0, gb1, sync);
}

// Round 7
// 3118.016 us; speedup vs baseline: 4.5936x; 1.8936x over previous
//
#include <hip/hip_runtime.h>

#define SEQ 999
#define DTC 0.01f
#define NXW 125
#define NW1 64
// padded sync dword indices (128B stride to kill false sharing)
#define IDX_C0  0
#define IDX_C1  32
#define IDX_CW1 64
#define IDX_FLG 96          // flag b at IDX_FLG + 32*b
#define SYNC_DWORDS 4096

typedef _Float16 h2 __attribute__((ext_vector_type(2)));

__device__ __forceinline__ h2 u2h(unsigned u){ return __builtin_bit_cast(h2,u); }

// v_dot2_f32_f16: h pair in SGPR (src0), weight VGPR tied (stays resident), acc tied.
#define DOT(ACC,HS,WV)  asm("v_dot2_f32_f16 %0, %2, %1, %0" : "+v"(ACC), "+v"(WV) : "s"(HS))
#define DOTL(ACC,HS,WU) asm("v_dot2_f32_f16 %0, %1, %2, %0" : "+v"(ACC) : "s"(HS), "v"(WU))
// AGPR-resident weight (proven round 5): explicit read then dot.
#define AGW(AG,V) asm("v_accvgpr_write_b32 %0, %1" : "=a"(AG) : "v"(V))
#define DOTA(ACC,HS,AG) do{ unsigned _tw;                                  \
  asm("v_accvgpr_read_b32 %0, %1" : "=v"(_tw) : "a"(AG));                  \
  asm("v_dot2_f32_f16 %0, %1, %2, %0" : "+v"(ACC) : "s"(HS), "v"(_tw)); }while(0)

#define RL(COMP,LANE) ((unsigned)__builtin_amdgcn_readlane((int)(COMP),(LANE)))

__device__ __forceinline__ float softplusf(float x){
  return fmaxf(x,0.f) + log1pf(__expf(-fabsf(x)));
}
__device__ __forceinline__ float sigmoidf(float x){ return 1.f/(1.f+__expf(-x)); }
__device__ __forceinline__ float tanh_fast(float x){
  float e = __expf(-2.f*x); return (1.f-e)/(1.f+e);
}

// relaxed poll + final acquire (acquire does the cache-invalidate once)
template<int SLP>
__device__ __forceinline__ void waitge(unsigned* p, unsigned v){
  if (__hip_atomic_load(p,__ATOMIC_RELAXED,__HIP_MEMORY_SCOPE_AGENT) < v){
    do { __builtin_amdgcn_s_sleep(SLP); }
    while (__hip_atomic_load(p,__ATOMIC_RELAXED,__HIP_MEMORY_SCOPE_AGENT) < v);
  }
  (void)__hip_atomic_load(p,__ATOMIC_ACQUIRE,__HIP_MEMORY_SCOPE_AGENT);
}

__global__ void k_init(unsigned* sync){
  for (int i=threadIdx.x; i<SYNC_DWORDS; i+=512) sync[i] = 0u;
}

// whh0/whh1 -> ROW-MAJOR f16 pairs wR[r*128+j]=(W[r][2j],W[r][2j+1]); wih1 -> TRANSPOSED
__global__ void k_convert(const float* __restrict__ whh0, const float* __restrict__ wih1,
                          const float* __restrict__ whh1,
                          const float* __restrict__ bih0, const float* __restrict__ bhh0,
                          const float* __restrict__ bih1, const float* __restrict__ bhh1,
                          h2* __restrict__ whh0R, h2* __restrict__ wih1T, h2* __restrict__ whh1R,
                          float* __restrict__ bs0, float* __restrict__ bs1){
  int o = blockIdx.x*256 + threadIdx.x;
  if (o < 131072){
    int r = o >> 7, c2 = o & 127;
    const float* s = whh0 + r*256 + 2*c2;
    whh0R[o] = h2{(_Float16)s[0], (_Float16)s[1]};
  } else if (o < 262144){
    int oo = o - 131072; int r = oo & 1023, c2 = oo >> 10;
    const float* s = wih1 + r*256 + 2*c2;
    wih1T[oo] = h2{(_Float16)s[0], (_Float16)s[1]};
  } else if (o < 393216){
    int oo = o - 262144; int r = oo >> 7, c2 = oo & 127;
    const float* s = whh1 + r*256 + 2*c2;
    whh1R[oo] = h2{(_Float16)s[0], (_Float16)s[1]};
  } else if (o < 394240){
    int r = o - 393216; bs0[r] = bih0[r] + bhh0[r];
  } else if (o < 395264){
    int r = o - 394240; bs1[r] = bih1[r] + bhh1[r];
  }
}

// ===== LSTM layer on ONE CU: 512 thr, rows (tid, tid+512); weights 44V+52A+32LDS per row =====
template<int MODE>
__device__ void do_layer(const h2* __restrict__ wR, const float* __restrict__ wih0,
                         const float* __restrict__ bs, const float* __restrict__ X,
                         const float* __restrict__ xw1,
                         _Float16* __restrict__ h0h, float* __restrict__ h1f,
                         unsigned* prog, unsigned* sync,
                         uint4 (*wlds)[8][512], float* xlds, float* exch,
                         _Float16 (*hbuf)[256])
{
  const int tid = threadIdx.x;
  const int r0 = tid, r1 = tid + 512;

  unsigned wvA[44], wvB[44];
  unsigned agA[52], agB[52];
  {
    const uint4* s0 = (const uint4*)(wR + (size_t)r0*128);
    const uint4* s1 = (const uint4*)(wR + (size_t)r1*128);
#pragma unroll
    for (int q=0;q<11;++q){
      uint4 v0=s0[q], v1=s1[q];
      wvA[4*q]=v0.x; wvA[4*q+1]=v0.y; wvA[4*q+2]=v0.z; wvA[4*q+3]=v0.w;
      wvB[4*q]=v1.x; wvB[4*q+1]=v1.y; wvB[4*q+2]=v1.z; wvB[4*q+3]=v1.w;
    }
#pragma unroll
    for (int q=0;q<13;++q){
      uint4 v0=s0[11+q], v1=s1[11+q];
      AGW(agA[4*q],v0.x); AGW(agA[4*q+1],v0.y); AGW(agA[4*q+2],v0.z); AGW(agA[4*q+3],v0.w);
      AGW(agB[4*q],v1.x); AGW(agB[4*q+1],v1.y); AGW(agB[4*q+2],v1.z); AGW(agB[4*q+3],v1.w);
    }
#pragma unroll
    for (int q=0;q<8;++q){ wlds[0][q][tid]=s0[24+q]; wlds[1][q][tid]=s1[24+q]; }
  }

  float bsA=0.f,bsB=0.f,wxA0=0.f,wxA1=0.f,wxB0=0.f,wxB1=0.f, nxA=0.f,nxB=0.f;
  if (MODE==0){
    bsA=bs[r0]; bsB=bs[r1];
    wxA0=wih0[2*r0]; wxA1=wih0[2*r0+1];
    wxB0=wih0[2*r1]; wxB1=wih0[2*r1+1];
    for (int i=tid;i<2*SEQ;i+=512) xlds[i]=X[i];
  } else {
    if (tid==0) waitge<2>(&sync[IDX_FLG+0], 1u);     // xw chunk 0 ready
  }
  __syncthreads();
  if (MODE==1){ nxA = xw1[r0]; nxB = xw1[r1]; }

  float c = 0.f;
  uint4 hv = {0u,0u,0u,0u};
  float nx2A=0.f, nx2B=0.f;

#pragma unroll 1
  for (int t=0;t<SEQ;++t){
    // gate + prefetch xw1[t+1] (MODE1); acquire ordered BEFORE the loads via barrier
    if (MODE==1 && t+1<SEQ){
      if (((t+1)&7)==0){
        if (tid==0) waitge<2>(&sync[IDX_FLG + ((t+1)>>3)*32], 1u);
        __syncthreads();
      }
      nx2A = xw1[(size_t)(t+1)*1024 + r0];
      nx2B = xw1[(size_t)(t+1)*1024 + r1];
    }

    float a0, b0=0.f, a1, b1=0.f;
    if (MODE==0){
      float2 xv = *(const float2*)&xlds[2*t];
      a0 = fmaf(wxA1, xv.y, fmaf(wxA0, xv.x, bsA));
      a1 = fmaf(wxB1, xv.y, fmaf(wxB0, xv.x, bsB));
    } else { a0 = nxA; a1 = nxB; }

    // cols 0..43: VGPR-resident
#pragma unroll
    for (int q=0;q<11;++q){
      unsigned hA=RL(hv.x,q), hB=RL(hv.y,q), hC=RL(hv.z,q), hD=RL(hv.w,q);
      DOT(a0,hA,wvA[4*q  ]); DOT(a1,hA,wvB[4*q  ]);
      DOT(b0,hB,wvA[4*q+1]); DOT(b1,hB,wvB[4*q+1]);
      DOT(a0,hC,wvA[4*q+2]); DOT(a1,hC,wvB[4*q+2]);
      DOT(b0,hD,wvA[4*q+3]); DOT(b1,hD,wvB[4*q+3]);
    }
    // cols 44..95: AGPR-resident
#pragma unroll
    for (int q=11;q<24;++q){
      unsigned hA=RL(hv.x,q), hB=RL(hv.y,q), hC=RL(hv.z,q), hD=RL(hv.w,q);
      const int k = 4*(q-11);
      DOTA(a0,hA,agA[k  ]); DOTA(a1,hA,agB[k  ]);
      DOTA(b0,hB,agA[k+1]); DOTA(b1,hB,agB[k+1]);
      DOTA(a0,hC,agA[k+2]); DOTA(a1,hC,agB[k+2]);
      DOTA(b0,hD,agA[k+3]); DOTA(b1,hD,agB[k+3]);
    }
    // cols 96..127: LDS-resident; address laundered so reads stay in-loop (NOT volatile)
    {
      unsigned lofs = tid*16;
      asm volatile("" : "+v"(lofs));
      const char* wb0 = (const char*)(&wlds[0][0][0]) + lofs;
      const char* wb1 = wb0 + 65536;
#pragma unroll
      for (int q=0;q<8;++q){
        uint4 u0 = *(const uint4*)(wb0 + q*8192);
        uint4 u1 = *(const uint4*)(wb1 + q*8192);
        const int qq = 24+q;
        unsigned hA=RL(hv.x,qq), hB=RL(hv.y,qq), hC=RL(hv.z,qq), hD=RL(hv.w,qq);
        DOTL(a0,hA,u0.x); DOTL(a1,hA,u1.x);
        DOTL(b0,hB,u0.y); DOTL(b1,hB,u1.y);
        DOTL(a0,hC,u0.z); DOTL(a1,hC,u1.z);
        DOTL(b0,hD,u0.w); DOTL(b1,hD,u1.w);
      }
    }
    a0 += b0; a1 += b1;

    // tid<256: rows (i_k, g_k) -> exch = i*g ; tid>=256: rows (f_k, o_k)
    float f_=0.f, o_=0.f;
    if (tid < 256) exch[tid] = sigmoidf(a0) * tanh_fast(a1);
    else          { f_ = sigmoidf(a0); o_ = sigmoidf(a1); }
    __syncthreads();                                  // B1
    if (tid >= 256){
      const int k = tid - 256;
      c = fmaf(f_, c, exch[k]);
      float hval = o_ * tanh_fast(c);
      _Float16 h16 = (_Float16)hval;
      hbuf[t&1][k] = h16;
      if (MODE==0) h0h[t*256+k] = h16;
      else         h1f[t*256+k] = hval;
    }
    __syncthreads();                                  // B2 (drains all stores)
    if (tid==0 && ((t&7)==7 || t==SEQ-1))
      __hip_atomic_store(prog,(unsigned)(t+1),__ATOMIC_RELEASE,__HIP_MEMORY_SCOPE_AGENT);
    hv = *(const uint4*)((const char*)hbuf[t&1] + (tid&31)*16);
    nxA = nx2A; nxB = nx2B;
  }
}

// xw chunk worker (proven round 6)
__device__ void do_xw(int b, const h2* __restrict__ wih1T, const float* __restrict__ bs1,
                      const _Float16* __restrict__ h0h, float* __restrict__ xw1,
                      unsigned* sync)
{
  const int tid = threadIdx.x;
  const int t0 = 8*b;
  const int tend = (t0+8 < SEQ) ? t0+8 : SEQ;
  if (tid==0) waitge<32>(&sync[IDX_C0], (unsigned)tend);
  __syncthreads();
  const float bA = bs1[tid], bB = bs1[tid+512];
#pragma unroll 1
  for (int t=t0;t<tend;++t){
    const uint4* hv4 = (const uint4*)(h0h + (size_t)t*256);
    float a0=bA, a1=bB, b0=0.f, b1=0.f;
#pragma unroll
    for (int q=0;q<32;++q){
      uint4 hv = hv4[q];
      h2 hx=u2h(hv.x), hy=u2h(hv.y), hz=u2h(hv.z), hw=u2h(hv.w);
      a0 = __builtin_amdgcn_fdot2(hx, wih1T[(4*q+0)*1024+tid    ], a0, false);
      b0 = __builtin_amdgcn_fdot2(hy, wih1T[(4*q+1)*1024+tid    ], b0, false);
      a0 = __builtin_amdgcn_fdot2(hz, wih1T[(4*q+2)*1024+tid    ], a0, false);
      b0 = __builtin_amdgcn_fdot2(hw, wih1T[(4*q+3)*1024+tid    ], b0, false);
      a1 = __builtin_amdgcn_fdot2(hx, wih1T[(4*q+0)*1024+tid+512], a1, false);
      b1 = __builtin_amdgcn_fdot2(hy, wih1T[(4*q+1)*1024+tid+512], b1, false);
      a1 = __builtin_amdgcn_fdot2(hz, wih1T[(4*q+2)*1024+tid+512], a1, false);
      b1 = __builtin_amdgcn_fdot2(hw, wih1T[(4*q+3)*1024+tid+512], b1, false);
    }
    xw1[(size_t)t*1024 + tid      ] = a0 + b0;
    xw1[(size_t)t*1024 + tid + 512] = a1 + b1;
  }
  __syncthreads();
  if (tid==0)
    __hip_atomic_store(&sync[IDX_FLG + 32*b], 1u, __ATOMIC_RELEASE, __HIP_MEMORY_SCOPE_AGENT);
}

// W1 streamer: 4 rows/block, gated on L1 progress at 128-step granularity (proven)
__device__ void do_w1(int w, const float* __restrict__ W1, const float* __restrict__ b1,
                      const float* __restrict__ h1f, float* __restrict__ z1,
                      unsigned* sync, float* red)
{
  const int tid = threadIdx.x;
#pragma unroll 1
  for (int rr=0;rr<4;++rr){
    const int j = w*4 + rr;
    const float* wrow = W1 + (size_t)j*(SEQ*256);
    float acc = 0.f;
#pragma unroll 1
    for (int kc=0;kc<8;++kc){
      const int lo = kc*128, hi = (kc==7) ? SEQ : lo+128;
      if (tid==0) waitge<64>(&sync[IDX_C1], (unsigned)hi);
      __syncthreads();
      const float4* w4 = (const float4*)(wrow + lo*256);
      const float4* h4 = (const float4*)(h1f + lo*256);
      const int n4 = (hi-lo)*64;
      for (int q=tid; q<n4; q+=512){
        float4 a=w4[q], b=h4[q];
        acc=fmaf(a.x,b.x,acc); acc=fmaf(a.y,b.y,acc);
        acc=fmaf(a.z,b.z,acc); acc=fmaf(a.w,b.w,acc);
      }
      __syncthreads();
    }
    red[tid]=acc; __syncthreads();
    for (int s=256;s>0;s>>=1){ if(tid<s) red[tid]+=red[tid+s]; __syncthreads(); }
    if (tid==0) z1[j] = softplusf(red[0] + b1[j]);
    __syncthreads();
  }
  if (tid==0)
    __hip_atomic_fetch_add(&sync[IDX_CW1], 1u, __ATOMIC_RELEASE, __HIP_MEMORY_SCOPE_AGENT);
}

__device__ void do_head(const float* __restrict__ W2, const float* __restrict__ b2,
                        const float* __restrict__ W3, const float* __restrict__ b3,
                        const float* __restrict__ z1, const float* __restrict__ data,
                        float* __restrict__ out, unsigned* sync, float* red)
{
  const int tid = threadIdx.x;
  if (tid==0) waitge<64>(&sync[IDX_CW1], (unsigned)NW1);
  __syncthreads();
  if (tid<256) red[tid] = z1[tid];
  __syncthreads();
  if (tid<128){
    float acc = b2[tid];
#pragma unroll 4
    for (int k=0;k<256;++k) acc = fmaf(W2[tid*256+k], red[k], acc);
    red[256+tid] = softplusf(acc);
  }
  __syncthreads();
  if (tid<4){
    float a = b3[tid];
#pragma unroll 4
    for (int k=0;k<128;++k) a = fmaf(W3[tid*128+k], red[256+k], a);
    red[384+tid] = a;
  }
  __syncthreads();
  if (tid==0){
    float a=red[384], b=red[385], cc=red[386], d=red[387];
    float R=data[0], J=data[1];
#pragma unroll 1
    for (int t=0;t<SEQ;++t){
      float RJ=R*J;
      float Rn = R + DTC*(a*R - b*RJ);
      float Jn = J + DTC*(d*RJ - cc*J);
      out[2*t]=Rn; out[2*t+1]=Jn;
      R=Rn; J=Jn;
    }
  }
}

// roles: 0=L0 | 1=L1 | 2..126 xw | 127..190 W1 | 191 head. 143KB LDS -> 1 block/CU.
__global__ __launch_bounds__(512,1)
void k_fused(const h2* __restrict__ whh0R, const h2* __restrict__ wih1T,
             const h2* __restrict__ whh1R, const float* __restrict__ bs0,
             const float* __restrict__ bs1, const float* __restrict__ Wih0,
             const float* __restrict__ X, _Float16* h0h, float* xw1, float* h1f,
             float* z1, const float* __restrict__ W1, const float* __restrict__ b1,
             const float* __restrict__ W2, const float* __restrict__ b2,
             const float* __restrict__ W3, const float* __restrict__ b3,
             const float* __restrict__ data, float* out, unsigned* sync)
{
  __shared__ uint4 wlds[2][8][512];                 // 128 KB weight cols 96..127
  __shared__ float xlds[2*SEQ];                     // 8 KB
  __shared__ float exch[256];                       // 1 KB
  __shared__ __align__(16) _Float16 hbuf[2][256];   // 1 KB
  __shared__ float red[512];                        // 2 KB

  const int role = blockIdx.x;
  if (role == 0)
    do_layer<0>(whh0R, Wih0, bs0, X, nullptr, h0h, nullptr,
                &sync[IDX_C0], sync, wlds, xlds, exch, hbuf);
  else if (role == 1)
    do_layer<1>(whh1R, nullptr, nullptr, nullptr, xw1, nullptr, h1f,
                &sync[IDX_C1], sync, wlds, xlds, exch, hbuf);
  else if (role < 2+NXW)
    do_xw(role-2, wih1T, bs1, h0h, xw1, sync);
  else if (role < 2+NXW+NW1)
    do_w1(role-(2+NXW), W1, b1, h1f, z1, sync, red);
  else
    do_head(W2, b2, W3, b3, z1, data, out, sync, red);
}

extern "C" void kernel_launch(void* const* d_in, const int* in_sizes, int n_in,
                              void* d_out, int out_size, void* d_ws, size_t ws_size,
                              hipStream_t stream){
  const float* X    = (const float*)d_in[0];
  const float* data = (const float*)d_in[1];
  const float* Wih0 = (const float*)d_in[2];
  const float* Whh0 = (const float*)d_in[3];
  const float* bih0 = (const float*)d_in[4];
  const float* bhh0 = (const float*)d_in[5];
  const float* Wih1 = (const float*)d_in[6];
  const float* Whh1 = (const float*)d_in[7];
  const float* bih1 = (const float*)d_in[8];
  const float* bhh1 = (const float*)d_in[9];
  const float* W1   = (const float*)d_in[10];
  const float* b1   = (const float*)d_in[11];
  const float* W2   = (const float*)d_in[12];
  const float* b2   = (const float*)d_in[13];
  const float* W3   = (const float*)d_in[14];
  const float* b3   = (const float*)d_in[15];
  float* out = (float*)d_out;

  char* w = (char*)d_ws;
  h2*       whh0R = (h2*)(w + 0);              // 512 KB row-major f16
  h2*       wih1T = (h2*)(w + 524288);         // 512 KB transposed f16
  h2*       whh1R = (h2*)(w + 1048576);        // 512 KB row-major f16
  float*    bs0   = (float*)(w + 1572864);     // 4 KB
  float*    bs1   = (float*)(w + 1576960);     // 4 KB
  _Float16* h0h   = (_Float16*)(w + 1581056);  // 511,488 B
  float*    xw1   = (float*)(w + 2097152);     // 4,091,904 B
  float*    h1f   = (float*)(w + 6189056);     // 1,022,976 B
  float*    z1    = (float*)(w + 7212032);     // 1 KB
  unsigned* sync  = (unsigned*)(w + 7213056);  // 16 KB padded counters/flags

  k_init<<<1, 512, 0, stream>>>(sync);
  k_convert<<<1544, 256, 0, stream>>>(Whh0, Wih1, Whh1, bih0, bhh0, bih1, bhh1,
                                      whh0R, wih1T, whh1R, bs0, bs1);
  k_fused<<<2+NXW+NW1+1, 512, 0, stream>>>(whh0R, wih1T, whh1R, bs0, bs1, Wih0, X,
                                           h0h, xw1, h1f, z1, W1, b1, W2, b2, W3, b3,
                                           data, out, sync);
}

// Round 8
// 2516.806 us; speedup vs baseline: 5.6909x; 1.2389x over previous
//
#include <hip/hip_runtime.h>

#define SEQ 999
#define DTC 0.01f
#define NXW 125
#define NW1 64
// padded sync dword indices (128B stride)
#define IDX_C0  0
#define IDX_C1  32
#define IDX_CW1 64
#define IDX_FLG 96          // flag b at IDX_FLG + 32*b
#define SYNC_DWORDS 4096

typedef _Float16 h2 __attribute__((ext_vector_type(2)));

__device__ __forceinline__ h2 u2h(unsigned u){ return __builtin_bit_cast(h2,u); }

// v_dot2_f32_f16, ALL-VGPR operands (no SGPR reads in the hot loop).
// Weight tied ("+v") so it must stay register-resident (proven r5/r7).
#define DOT(ACC,HV,WV)  asm("v_dot2_f32_f16 %0, %2, %1, %0" : "+v"(ACC), "+v"(WV) : "v"(HV))
#define DOTL(ACC,HV,WU) asm("v_dot2_f32_f16 %0, %1, %2, %0" : "+v"(ACC) : "v"(HV), "v"(WU))
// AGPR-resident weight (proven r5/r7): explicit read then dot.
#define AGW(AG,V) asm("v_accvgpr_write_b32 %0, %1" : "=a"(AG) : "v"(V))
#define DOTA(ACC,HV,AG) do{ unsigned _tw;                                  \
  asm("v_accvgpr_read_b32 %0, %1" : "=v"(_tw) : "a"(AG));                  \
  asm("v_dot2_f32_f16 %0, %1, %2, %0" : "+v"(ACC) : "v"(HV), "v"(_tw)); }while(0)

__device__ __forceinline__ float softplusf(float x){
  return fmaxf(x,0.f) + log1pf(__expf(-fabsf(x)));
}
__device__ __forceinline__ float sigmoidf(float x){ return 1.f/(1.f+__expf(-x)); }
__device__ __forceinline__ float tanh_fast(float x){
  float e = __expf(-2.f*x); return (1.f-e)/(1.f+e);
}

template<int SLP>
__device__ __forceinline__ void waitge(unsigned* p, unsigned v){
  if (__hip_atomic_load(p,__ATOMIC_RELAXED,__HIP_MEMORY_SCOPE_AGENT) < v){
    do { __builtin_amdgcn_s_sleep(SLP); }
    while (__hip_atomic_load(p,__ATOMIC_RELAXED,__HIP_MEMORY_SCOPE_AGENT) < v);
  }
  (void)__hip_atomic_load(p,__ATOMIC_ACQUIRE,__HIP_MEMORY_SCOPE_AGENT);
}

__global__ void k_init(unsigned* sync){
  for (int i=threadIdx.x; i<SYNC_DWORDS; i+=512) sync[i] = 0u;
}

// whh0/whh1 -> ROW-MAJOR f16 pairs wR[row*128+c2]; wih1 -> TRANSPOSED (for do_xw)
__global__ void k_convert(const float* __restrict__ whh0, const float* __restrict__ wih1,
                          const float* __restrict__ whh1,
                          const float* __restrict__ bih0, const float* __restrict__ bhh0,
                          const float* __restrict__ bih1, const float* __restrict__ bhh1,
                          h2* __restrict__ whh0R, h2* __restrict__ wih1T, h2* __restrict__ whh1R,
                          float* __restrict__ bs0, float* __restrict__ bs1){
  int o = blockIdx.x*256 + threadIdx.x;
  if (o < 131072){
    int r = o >> 7, c2 = o & 127;
    const float* s = whh0 + r*256 + 2*c2;
    whh0R[o] = h2{(_Float16)s[0], (_Float16)s[1]};
  } else if (o < 262144){
    int oo = o - 131072; int r = oo & 1023, c2 = oo >> 10;
    const float* s = wih1 + r*256 + 2*c2;
    wih1T[oo] = h2{(_Float16)s[0], (_Float16)s[1]};
  } else if (o < 393216){
    int oo = o - 262144; int r = oo >> 7, c2 = oo & 127;
    const float* s = whh1 + r*256 + 2*c2;
    whh1R[oo] = h2{(_Float16)s[0], (_Float16)s[1]};
  } else if (o < 394240){
    int r = o - 393216; bs0[r] = bih0[r] + bhh0[r];
  } else if (o < 395264){
    int r = o - 394240; bs1[r] = bih1[r] + bhh1[r];
  }
}

// ===== LSTM layer, ONE CU, K-split: thread (k = tid&255, half = tid>>8) owns unit k's
// 4 gate rows over h-columns [128*half, 128*half+128). Per row 64 h2: 16 V + 32 AGPR + 16 LDS.
// h broadcast: 16 wave-uniform ds_read_b128 per thread (per-thread h-half only).
// Partner combine: one float4 LDS exchange; thread k<256 owns c,h privately.

// load one gate row's 64 h2: q0..3 -> V, q4..11 -> AGPR, q12..15 -> LDS
#define LOADROW(R, VV, AA) do{                                                      \
  const uint4* _src = (const uint4*)(wR + (size_t)((((R)<<8)+k)*128 + (half<<6)));  \
  _Pragma("unroll")                                                                 \
  for (int q=0;q<4;++q){ uint4 u=_src[q];                                           \
    VV[4*q]=u.x; VV[4*q+1]=u.y; VV[4*q+2]=u.z; VV[4*q+3]=u.w; }                     \
  _Pragma("unroll")                                                                 \
  for (int q=4;q<12;++q){ uint4 u=_src[q]; const int b=4*(q-4);                     \
    AGW(AA[b],u.x); AGW(AA[b+1],u.y); AGW(AA[b+2],u.z); AGW(AA[b+3],u.w); }         \
  _Pragma("unroll")                                                                 \
  for (int q=12;q<16;++q) wldsW[half][(R)*4+(q-12)][k] = _src[q];                   \
}while(0)

#define D16V(J) do{                                                                  \
  DOT(ai,hA.x,v0[J]);   DOT(af,hA.x,v1[J]);   DOT(agv,hA.x,v2[J]);   DOT(ao,hA.x,v3[J]);     \
  DOT(ai,hA.y,v0[(J)+1]); DOT(af,hA.y,v1[(J)+1]); DOT(agv,hA.y,v2[(J)+1]); DOT(ao,hA.y,v3[(J)+1]); \
  DOT(ai,hA.z,v0[(J)+2]); DOT(af,hA.z,v1[(J)+2]); DOT(agv,hA.z,v2[(J)+2]); DOT(ao,hA.z,v3[(J)+2]); \
  DOT(ai,hA.w,v0[(J)+3]); DOT(af,hA.w,v1[(J)+3]); DOT(agv,hA.w,v2[(J)+3]); DOT(ao,hA.w,v3[(J)+3]); \
}while(0)

#define D16A(J) do{                                                                  \
  DOTA(ai,hA.x,a0g[J]);   DOTA(af,hA.x,a1g[J]);   DOTA(agv,hA.x,a2g[J]);   DOTA(ao,hA.x,a3g[J]);     \
  DOTA(ai,hA.y,a0g[(J)+1]); DOTA(af,hA.y,a1g[(J)+1]); DOTA(agv,hA.y,a2g[(J)+1]); DOTA(ao,hA.y,a3g[(J)+1]); \
  DOTA(ai,hA.z,a0g[(J)+2]); DOTA(af,hA.z,a1g[(J)+2]); DOTA(agv,hA.z,a2g[(J)+2]); DOTA(ao,hA.z,a3g[(J)+2]); \
  DOTA(ai,hA.w,a0g[(J)+3]); DOTA(af,hA.w,a1g[(J)+3]); DOTA(agv,hA.w,a2g[(J)+3]); DOTA(ao,hA.w,a3g[(J)+3]); \
}while(0)

#define D16L(C) do{                                                                  \
  uint4 u0=wldsW[half][0*4+(C)][k], u1=wldsW[half][1*4+(C)][k];                       \
  uint4 u2=wldsW[half][2*4+(C)][k], u3=wldsW[half][3*4+(C)][k];                       \
  DOTL(ai,hA.x,u0.x); DOTL(af,hA.x,u1.x); DOTL(agv,hA.x,u2.x); DOTL(ao,hA.x,u3.x);    \
  DOTL(ai,hA.y,u0.y); DOTL(af,hA.y,u1.y); DOTL(agv,hA.y,u2.y); DOTL(ao,hA.y,u3.y);    \
  DOTL(ai,hA.z,u0.z); DOTL(af,hA.z,u1.z); DOTL(agv,hA.z,u2.z); DOTL(ao,hA.z,u3.z);    \
  DOTL(ai,hA.w,u0.w); DOTL(af,hA.w,u1.w); DOTL(agv,hA.w,u2.w); DOTL(ao,hA.w,u3.w);    \
}while(0)

template<int MODE>
__device__ void do_layer(const h2* __restrict__ wR, const float* __restrict__ wih0,
                         const float* __restrict__ bs, const float* __restrict__ X,
                         const float* __restrict__ xw1,
                         _Float16* __restrict__ h0h, float* __restrict__ h1f,
                         unsigned* prog, unsigned* sync,
                         uint4 (*wldsW)[16][256], _Float16 (*hbufS)[256],
                         float4* pexch, float* xlds)
{
  const int tid  = threadIdx.x;
  const int k    = tid & 255;
  const int half = tid >> 8;

  unsigned v0[16], v1[16], v2[16], v3[16];     // 64 arch VGPR weights
  unsigned a0g[32], a1g[32], a2g[32], a3g[32]; // 128 AGPR weights
  LOADROW(0, v0, a0g);
  LOADROW(1, v1, a1g);
  LOADROW(2, v2, a2g);
  LOADROW(3, v3, a3g);

  float wxa0=0,wxa1=0,wxa2=0,wxa3=0, wxb0=0,wxb1=0,wxb2=0,wxb3=0, bv0=0,bv1=0,bv2=0,bv3=0;
  if (MODE==0){
    if (half==1){
      wxa0=wih0[((0<<8)+k)*2]; wxb0=wih0[((0<<8)+k)*2+1]; bv0=bs[(0<<8)+k];
      wxa1=wih0[((1<<8)+k)*2]; wxb1=wih0[((1<<8)+k)*2+1]; bv1=bs[(1<<8)+k];
      wxa2=wih0[((2<<8)+k)*2]; wxb2=wih0[((2<<8)+k)*2+1]; bv2=bs[(2<<8)+k];
      wxa3=wih0[((3<<8)+k)*2]; wxb3=wih0[((3<<8)+k)*2+1]; bv3=bs[(3<<8)+k];
    }
    for (int i=tid;i<2*SEQ;i+=512) xlds[i]=X[i];
  }
  if (tid < 256) hbufS[0][tid] = (_Float16)0.f;
  __syncthreads();

  float4 nx = {0,0,0,0}, nx2 = {0,0,0,0};
  if (MODE==1){
    if (tid==0) waitge<2>(&sync[IDX_FLG+0], 1u);
    __syncthreads();
    if (half==0) nx = *(const float4*)&xw1[(size_t)(k<<2)];
  }
  float c = 0.f;

#pragma unroll 1
  for (int t=0;t<SEQ;++t){
    if (MODE==1 && t+1<SEQ){
      if (((t+1)&7)==0){
        if (tid==0) waitge<2>(&sync[IDX_FLG + ((t+1)>>3)*32], 1u);
        __syncthreads();
      }
      if (half==0) nx2 = *(const float4*)&xw1[(size_t)(t+1)*1024 + (k<<2)];
    }

    float ai, af, agv, ao;
    if (MODE==0){
      if (half==1){
        float2 xv = *(const float2*)&xlds[2*t];
        ai = fmaf(wxb0, xv.y, fmaf(wxa0, xv.x, bv0));
        af = fmaf(wxb1, xv.y, fmaf(wxa1, xv.x, bv1));
        agv= fmaf(wxb2, xv.y, fmaf(wxa2, xv.x, bv2));
        ao = fmaf(wxb3, xv.y, fmaf(wxa3, xv.x, bv3));
      } else { ai=af=agv=ao=0.f; }
    } else {
      if (half==0){ ai=nx.x; af=nx.y; agv=nx.z; ao=nx.w; }
      else        { ai=af=agv=ao=0.f; }
    }

    // --- dot phase: 16 wave-uniform b128 h-broadcast reads, pure VGPR dots ---
    const uint4* hb = (const uint4*)(&hbufS[t&1][0]) + (half<<4);
    uint4 hA = hb[0], hN;
    hN = hb[1];  D16V(0);   hA = hN;
    hN = hb[2];  D16V(4);   hA = hN;
    hN = hb[3];  D16V(8);   hA = hN;
    hN = hb[4];  D16V(12);  hA = hN;
    hN = hb[5];  D16A(0);   hA = hN;
    hN = hb[6];  D16A(4);   hA = hN;
    hN = hb[7];  D16A(8);   hA = hN;
    hN = hb[8];  D16A(12);  hA = hN;
    hN = hb[9];  D16A(16);  hA = hN;
    hN = hb[10]; D16A(20);  hA = hN;
    hN = hb[11]; D16A(24);  hA = hN;
    hN = hb[12]; D16A(28);  hA = hN;
    hN = hb[13]; D16L(0);   hA = hN;
    hN = hb[14]; D16L(1);   hA = hN;
    hN = hb[15]; D16L(2);   hA = hN;
                 D16L(3);

    if (half==1) pexch[k] = float4{ai, af, agv, ao};
    __syncthreads();                                  // B1: partials ready
    if (half==0){
      float4 p = pexch[k];
      ai += p.x; af += p.y; agv += p.z; ao += p.w;
      float i_ = sigmoidf(ai), f_ = sigmoidf(af);
      float g_ = tanh_fast(agv), o_ = sigmoidf(ao);
      c = fmaf(f_, c, i_*g_);
      float h = o_ * tanh_fast(c);
      hbufS[(t+1)&1][k] = (_Float16)h;
      if (MODE==0) h0h[t*256+k] = (_Float16)h;
      else         h1f[t*256+k] = h;
      nx = nx2;
    }
    __syncthreads();                                  // B2: h visible, stores drained
    if (tid==0 && ((t&7)==7 || t==SEQ-1))
      __hip_atomic_store(prog,(unsigned)(t+1),__ATOMIC_RELEASE,__HIP_MEMORY_SCOPE_AGENT);
  }
}

// xw chunk worker (proven r6/r7); OUTPUT layout now [t][unit][gate] for float4 reads
__device__ void do_xw(int b, const h2* __restrict__ wih1T, const float* __restrict__ bs1,
                      const _Float16* __restrict__ h0h, float* __restrict__ xw1,
                      unsigned* sync)
{
  const int tid = threadIdx.x;
  const int t0 = 8*b;
  const int tend = (t0+8 < SEQ) ? t0+8 : SEQ;
  if (tid==0) waitge<32>(&sync[IDX_C0], (unsigned)tend);
  __syncthreads();
  const float bA = bs1[tid], bB = bs1[tid+512];
  const int r0 = tid, r1 = tid + 512;
  const int d0 = ((r0&255)<<2) + (r0>>8);
  const int d1 = ((r1&255)<<2) + (r1>>8);
#pragma unroll 1
  for (int t=t0;t<tend;++t){
    const uint4* hv4 = (const uint4*)(h0h + (size_t)t*256);
    float a0=bA, a1=bB, b0=0.f, b1=0.f;
#pragma unroll
    for (int q=0;q<32;++q){
      uint4 hv = hv4[q];
      h2 hx=u2h(hv.x), hy=u2h(hv.y), hz=u2h(hv.z), hw=u2h(hv.w);
      a0 = __builtin_amdgcn_fdot2(hx, wih1T[(4*q+0)*1024+r0], a0, false);
      b0 = __builtin_amdgcn_fdot2(hy, wih1T[(4*q+1)*1024+r0], b0, false);
      a0 = __builtin_amdgcn_fdot2(hz, wih1T[(4*q+2)*1024+r0], a0, false);
      b0 = __builtin_amdgcn_fdot2(hw, wih1T[(4*q+3)*1024+r0], b0, false);
      a1 = __builtin_amdgcn_fdot2(hx, wih1T[(4*q+0)*1024+r1], a1, false);
      b1 = __builtin_amdgcn_fdot2(hy, wih1T[(4*q+1)*1024+r1], b1, false);
      a1 = __builtin_amdgcn_fdot2(hz, wih1T[(4*q+2)*1024+r1], a1, false);
      b1 = __builtin_amdgcn_fdot2(hw, wih1T[(4*q+3)*1024+r1], b1, false);
    }
    xw1[(size_t)t*1024 + d0] = a0 + b0;
    xw1[(size_t)t*1024 + d1] = a1 + b1;
  }
  __syncthreads();
  if (tid==0)
    __hip_atomic_store(&sync[IDX_FLG + 32*b], 1u, __ATOMIC_RELEASE, __HIP_MEMORY_SCOPE_AGENT);
}

// W1 streamer (proven r7)
__device__ void do_w1(int w, const float* __restrict__ W1, const float* __restrict__ b1,
                      const float* __restrict__ h1f, float* __restrict__ z1,
                      unsigned* sync, float* red)
{
  const int tid = threadIdx.x;
#pragma unroll 1
  for (int rr=0;rr<4;++rr){
    const int j = w*4 + rr;
    const float* wrow = W1 + (size_t)j*(SEQ*256);
    float acc = 0.f;
#pragma unroll 1
    for (int kc=0;kc<8;++kc){
      const int lo = kc*128, hi = (kc==7) ? SEQ : lo+128;
      if (tid==0) waitge<64>(&sync[IDX_C1], (unsigned)hi);
      __syncthreads();
      const float4* w4 = (const float4*)(wrow + lo*256);
      const float4* h4 = (const float4*)(h1f + lo*256);
      const int n4 = (hi-lo)*64;
      for (int q=tid; q<n4; q+=512){
        float4 a=w4[q], b=h4[q];
        acc=fmaf(a.x,b.x,acc); acc=fmaf(a.y,b.y,acc);
        acc=fmaf(a.z,b.z,acc); acc=fmaf(a.w,b.w,acc);
      }
      __syncthreads();
    }
    red[tid]=acc; __syncthreads();
    for (int s=256;s>0;s>>=1){ if(tid<s) red[tid]+=red[tid+s]; __syncthreads(); }
    if (tid==0) z1[j] = softplusf(red[0] + b1[j]);
    __syncthreads();
  }
  if (tid==0)
    __hip_atomic_fetch_add(&sync[IDX_CW1], 1u, __ATOMIC_RELEASE, __HIP_MEMORY_SCOPE_AGENT);
}

__device__ void do_head(const float* __restrict__ W2, const float* __restrict__ b2,
                        const float* __restrict__ W3, const float* __restrict__ b3,
                        const float* __restrict__ z1, const float* __restrict__ data,
                        float* __restrict__ out, unsigned* sync, float* red)
{
  const int tid = threadIdx.x;
  if (tid==0) waitge<64>(&sync[IDX_CW1], (unsigned)NW1);
  __syncthreads();
  if (tid<256) red[tid] = z1[tid];
  __syncthreads();
  if (tid<128){
    float acc = b2[tid];
#pragma unroll 4
    for (int kk=0;kk<256;++kk) acc = fmaf(W2[tid*256+kk], red[kk], acc);
    red[256+tid] = softplusf(acc);
  }
  __syncthreads();
  if (tid<4){
    float a = b3[tid];
#pragma unroll 4
    for (int kk=0;kk<128;++kk) a = fmaf(W3[tid*128+kk], red[256+kk], a);
    red[384+tid] = a;
  }
  __syncthreads();
  if (tid==0){
    float a=red[384], b=red[385], cc=red[386], d=red[387];
    float R=data[0], J=data[1];
#pragma unroll 1
    for (int t=0;t<SEQ;++t){
      float RJ=R*J;
      float Rn = R + DTC*(a*R - b*RJ);
      float Jn = J + DTC*(d*RJ - cc*J);
      out[2*t]=Rn; out[2*t+1]=Jn;
      R=Rn; J=Jn;
    }
  }
}

// roles: 0=L0 | 1=L1 | 2..126 xw | 127..190 W1 | 191 head. ~143KB LDS -> 1 block/CU.
__global__ __launch_bounds__(512,1)
void k_fused(const h2* __restrict__ whh0R, const h2* __restrict__ wih1T,
             const h2* __restrict__ whh1R, const float* __restrict__ bs0,
             const float* __restrict__ bs1, const float* __restrict__ Wih0,
             const float* __restrict__ X, _Float16* h0h, float* xw1, float* h1f,
             float* z1, const float* __restrict__ W1, const float* __restrict__ b1,
             const float* __restrict__ W2, const float* __restrict__ b2,
             const float* __restrict__ W3, const float* __restrict__ b3,
             const float* __restrict__ data, float* out, unsigned* sync)
{
  __shared__ __align__(16) uint4 wldsW[2][16][256];    // 128 KB (LDS weight cols)
  __shared__ __align__(16) _Float16 hbufS[2][256];     // 1 KB double-buffered h
  __shared__ __align__(16) float4 pexch[256];          // 4 KB partial-sum exchange
  __shared__ float xlds[2*SEQ];                        // 8 KB
  __shared__ float red[512];                           // 2 KB (w1/head)

  const int role = blockIdx.x;
  if (role == 0)
    do_layer<0>(whh0R, Wih0, bs0, X, nullptr, h0h, nullptr,
                &sync[IDX_C0], sync, wldsW, hbufS, pexch, xlds);
  else if (role == 1)
    do_layer<1>(whh1R, nullptr, nullptr, nullptr, xw1, nullptr, h1f,
                &sync[IDX_C1], sync, wldsW, hbufS, pexch, xlds);
  else if (role < 2+NXW)
    do_xw(role-2, wih1T, bs1, h0h, xw1, sync);
  else if (role < 2+NXW+NW1)
    do_w1(role-(2+NXW), W1, b1, h1f, z1, sync, red);
  else
    do_head(W2, b2, W3, b3, z1, data, out, sync, red);
}

extern "C" void kernel_launch(void* const* d_in, const int* in_sizes, int n_in,
                              void* d_out, int out_size, void* d_ws, size_t ws_size,
                              hipStream_t stream){
  const float* X    = (const float*)d_in[0];
  const float* data = (const float*)d_in[1];
  const float* Wih0 = (const float*)d_in[2];
  const float* Whh0 = (const float*)d_in[3];
  const float* bih0 = (const float*)d_in[4];
  const float* bhh0 = (const float*)d_in[5];
  const float* Wih1 = (const float*)d_in[6];
  const float* Whh1 = (const float*)d_in[7];
  const float* bih1 = (const float*)d_in[8];
  const float* bhh1 = (const float*)d_in[9];
  const float* W1   = (const float*)d_in[10];
  const float* b1   = (const float*)d_in[11];
  const float* W2   = (const float*)d_in[12];
  const float* b2   = (const float*)d_in[13];
  const float* W3   = (const float*)d_in[14];
  const float* b3   = (const float*)d_in[15];
  float* out = (float*)d_out;

  char* w = (char*)d_ws;
  h2*       whh0R = (h2*)(w + 0);              // 512 KB row-major f16
  h2*       wih1T = (h2*)(w + 524288);         // 512 KB transposed f16
  h2*       whh1R = (h2*)(w + 1048576);        // 512 KB row-major f16
  float*    bs0   = (float*)(w + 1572864);     // 4 KB
  float*    bs1   = (float*)(w + 1576960);     // 4 KB
  _Float16* h0h   = (_Float16*)(w + 1581056);  // 511,488 B
  float*    xw1   = (float*)(w + 2097152);     // 4,091,904 B  [t][unit][gate]
  float*    h1f   = (float*)(w + 6189056);     // 1,022,976 B
  float*    z1    = (float*)(w + 7212032);     // 1 KB
  unsigned* sync  = (unsigned*)(w + 7213056);  // 16 KB padded counters/flags

  k_init<<<1, 512, 0, stream>>>(sync);
  k_convert<<<1544, 256, 0, stream>>>(Whh0, Wih1, Whh1, bih0, bhh0, bih1, bhh1,
                                      whh0R, wih1T, whh1R, bs0, bs1);
  k_fused<<<2+NXW+NW1+1, 512, 0, stream>>>(whh0R, wih1T, whh1R, bs0, bs1, Wih0, X,
                                           h0h, xw1, h1f, z1, W1, b1, W2, b2, W3, b3,
                                           data, out, sync);
}